// Round 11
// baseline (1038.943 us; speedup 1.0000x reference)
//
#include <hip/hip_runtime.h>
#include <hip/hip_cooperative_groups.h>
namespace cg = cooperative_groups;

// ---------------------------------------------------------------------------
// QMWLNPairwiseAtomClassifier — round 11 (= round 9 + checked cooperative
// fusion with occupancy-sized grid and fallback to the round-9 sequence):
//  * wln_fused cooperative kernel (3x{L1,nei,L2} + SaSelf + kernels2 + UV)
//  * grid = min(768, occupancy*256); hipLaunchCooperativeKernel return code
//    CHECKED; on failure -> verified round-9 separate-dispatch path
//  * score/pairsum/seg_final identical to round 9 (verified)
// ---------------------------------------------------------------------------

constexpr int cB = 16, cNR = 96, cNG = 64;
constexpr int cAF = 98, cBF = 6;
constexpr int cH = 300, cQM = 160, cMAXNB = 10, cDEPTH = 4;
constexpr int cP = 2048;
constexpr int cF = 2 * cH + cQM;   // 760
constexpr int cD0 = cF + 10;       // 770

constexpr int Mres = cB * cNR;     // 1536
constexpr int Mrg  = cB * cNG;     // 1024

typedef __attribute__((ext_vector_type(8))) short v8s;
typedef __attribute__((ext_vector_type(4))) float v4f;

__device__ inline unsigned short f2bf(float f) {
  unsigned u = __float_as_uint(f);
  u += 0x7FFF + ((u >> 16) & 1);          // RNE
  return (unsigned short)(u >> 16);
}
__device__ inline float bf2f(unsigned short s) {
  return __uint_as_float(((unsigned)s) << 16);
}

// ---------------- prep: transpose+split all weights, zero pairsum -----------
struct PrepEnt { const float* W; unsigned short* hiT; unsigned short* loT;
                 int K, N, Kpad; };
struct PrepArgs { PrepEnt e[19]; int bases[20]; int nent; };

__global__ __launch_bounds__(256) void prep_k(PrepArgs pa)
{
  int g = blockIdx.x * 256 + threadIdx.x;
  if (g >= pa.bases[pa.nent]) return;
  int idx = 0;
  while (g >= pa.bases[idx + 1]) ++idx;
  PrepEnt p = pa.e[idx];
  int local = g - pa.bases[idx];
  if (!p.W) { ((float*)p.hiT)[local] = 0.f; return; }
  int n = local / p.Kpad, k = local - n * p.Kpad;
  float w = (k < p.K) ? p.W[(size_t)k * p.N + n] : 0.f;
  unsigned short h = f2bf(w);
  p.hiT[local] = h;
  p.loT[local] = f2bf(w - bf2f(h));
}

#define MFMA __builtin_amdgcn_mfma_f32_16x16x32_bf16

// ---------------- shared 32x64 GEMM tile body (verified round 9) ------------
__device__ __forceinline__ void gemm_tile(
    const float* __restrict__ A, const unsigned short* __restrict__ Wh,
    const unsigned short* __restrict__ Wl,
    const float* __restrict__ bias, int ldBias,
    float* __restrict__ C, int ldC,
    int K, int Kp, int N, int act, int m0, int n0,
    unsigned short (&Ah)[2][32][40], unsigned short (&Al)[2][32][40],
    unsigned short (&Bh)[2][64][40], unsigned short (&Bl)[2][64][40])
{
  int nT = Kp >> 5;
  int tid = threadIdx.x;
  bool doA = tid < 128;
  int smA = tid >> 2;
  int skA = (tid & 3) << 3;
  int smB = tid >> 2;
  int skB = (tid & 3) << 3;
  int gmA = m0 + smA;

  float areg[8];
  uint4 bh_reg, bl_reg;

  auto fetch = [&](int kv0) {
    if (doA) {
      int kk = kv0 + skA;
      const float* src = A + (size_t)gmA * K;
      if (((K & 3) == 0) && kk + 7 < K) {
        float4 v0 = *(const float4*)(src + kk);
        float4 v1 = *(const float4*)(src + kk + 4);
        areg[0]=v0.x; areg[1]=v0.y; areg[2]=v0.z; areg[3]=v0.w;
        areg[4]=v1.x; areg[5]=v1.y; areg[6]=v1.z; areg[7]=v1.w;
      } else {
#pragma unroll
        for (int j = 0; j < 8; ++j) areg[j] = (kk + j < K) ? src[kk + j] : 0.f;
      }
    }
    int gn = n0 + smB;
    int kkb = kv0 + skB;
    if (gn < N) {
      size_t o = (size_t)gn * Kp + kkb;
      bh_reg = *(const uint4*)(Wh + o);
      bl_reg = *(const uint4*)(Wl + o);
    } else {
      bh_reg = make_uint4(0,0,0,0); bl_reg = make_uint4(0,0,0,0);
    }
  };

  auto store = [&](int buf) {
    if (doA) {
      unsigned hs[8], ls[8];
#pragma unroll
      for (int j = 0; j < 8; ++j) {
        unsigned short hv = f2bf(areg[j]);
        hs[j] = hv;
        ls[j] = f2bf(areg[j] - bf2f(hv));
      }
      uint4 hh, ll;
      hh.x = hs[0] | (hs[1] << 16); hh.y = hs[2] | (hs[3] << 16);
      hh.z = hs[4] | (hs[5] << 16); hh.w = hs[6] | (hs[7] << 16);
      ll.x = ls[0] | (ls[1] << 16); ll.y = ls[2] | (ls[3] << 16);
      ll.z = ls[4] | (ls[5] << 16); ll.w = ls[6] | (ls[7] << 16);
      *(uint4*)&Ah[buf][smA][skA] = hh;
      *(uint4*)&Al[buf][smA][skA] = ll;
    }
    *(uint4*)&Bh[buf][smB][skB] = bh_reg;
    *(uint4*)&Bl[buf][smB][skB] = bl_reg;
  };

  int l = tid & 63, w = tid >> 6;
  int wr = (w >> 1) << 4;
  int wc = (w & 1) << 5;
  int arow = wr + (l & 15);
  int brow = wc + (l & 15);
  int kc = (l >> 4) << 3;

  v4f acc0 = {0,0,0,0}, acc1 = {0,0,0,0};

  fetch(0); store(0); __syncthreads();
  for (int t = 0; t < nT; ++t) {
    if (t + 1 < nT) fetch((t + 1) << 5);
    int cur = t & 1;
    v8s ah  = *(const v8s*)&Ah[cur][arow][kc];
    v8s al  = *(const v8s*)&Al[cur][arow][kc];
    v8s bh0 = *(const v8s*)&Bh[cur][brow][kc];
    v8s bh1 = *(const v8s*)&Bh[cur][brow + 16][kc];
    v8s bl0 = *(const v8s*)&Bl[cur][brow][kc];
    v8s bl1 = *(const v8s*)&Bl[cur][brow + 16][kc];
    acc0 = MFMA(ah, bh0, acc0, 0, 0, 0);
    acc0 = MFMA(ah, bl0, acc0, 0, 0, 0);
    acc0 = MFMA(al, bh0, acc0, 0, 0, 0);
    acc1 = MFMA(ah, bh1, acc1, 0, 0, 0);
    acc1 = MFMA(ah, bl1, acc1, 0, 0, 0);
    acc1 = MFMA(al, bh1, acc1, 0, 0, 0);
    if (t + 1 < nT) store(cur ^ 1);
    __syncthreads();
  }

  int rbase = m0 + wr + ((l >> 4) << 2);
  int cbase = n0 + wc + (l & 15);
  v4f accs[2] = {acc0, acc1};
#pragma unroll
  for (int fj = 0; fj < 2; ++fj) {
    int gn = cbase + fj * 16;
    if (gn >= N) continue;
    float* Cp = C + (size_t)rbase * ldC + gn;
    const float* Bp = bias ? bias + (size_t)rbase * ldBias + gn : nullptr;
#pragma unroll
    for (int r = 0; r < 4; ++r) {
      float v = accs[fj][r];
      if (Bp) v += Bp[(size_t)r * ldBias];
      if (act) v = fmaxf(v, 0.f);
      Cp[(size_t)r * ldC] = v;
    }
  }
}

// ---------------- standalone GEMM (round 9, used by prologue + fallback) ----
struct GArg {
  const float* A;
  const unsigned short* Wh; const unsigned short* Wl;
  const float* bias; int ldBias;
  float* C; int ldC;
  int M, K, Kp, act;
};
struct GArgs6 { GArg a[6]; };

__global__ __launch_bounds__(256) void gemm32(GArgs6 ga, int N)
{
  __shared__ unsigned short Ah[2][32][40];
  __shared__ unsigned short Al[2][32][40];
  __shared__ unsigned short Bh[2][64][40];
  __shared__ unsigned short Bl[2][64][40];
  GArg g = ga.a[blockIdx.z];
  int m0 = blockIdx.y * 32;
  if (m0 >= g.M) return;
  gemm_tile(g.A, g.Wh, g.Wl, g.bias, g.ldBias, g.C, g.ldC,
            g.K, g.Kp, N, g.act, m0, blockIdx.x * 64, Ah, Al, Bh, Bl);
}

// ---------------- fused WLN cooperative kernel ------------------------------
struct GemmP {
  const float *A0, *A1;
  const unsigned short *Wh0, *Wl0, *Wh1, *Wl1;
  const float *b0, *b1; int ldB;
  float *C0, *C1; int ldC;
  int K, Kp, N, act;
};

struct FusedArgs {
  float *afA_r, *afB_r, *afA_g, *afB_g;
  const float *Rb_r, *Rb_g, *Sb_r, *Sb_g;
  float *RaU1_r, *RaU1_g, *nei_r, *nei_g, *kern_r, *kern_g, *U, *V;
  const unsigned short *cat1_h0, *cat1_l0, *cat1_h1, *cat1_l1;
  const unsigned short *U1b_h0, *U1b_l0, *U1b_h1, *U1b_l1;
  const unsigned short *cat2_h0, *cat2_l0, *cat2_h1, *cat2_l1;
  const unsigned short *att_h, *att_l;
  const int *res_ag, *res_bg, *res_nnb;
  const int *rg_ag, *rg_bg, *rg_nnb;
  const float *res_mask, *rg_mask;
};

__device__ void run_gemm(const GemmP& p, int bid, int G,
                         unsigned short (&Ah)[2][32][40], unsigned short (&Al)[2][32][40],
                         unsigned short (&Bh)[2][64][40], unsigned short (&Bl)[2][64][40])
{
  int nx = (p.N + 63) >> 6;
  int tot0 = nx * (Mres / 32);
  int total = tot0 + nx * (Mrg / 32);
  for (int item = bid; item < total; item += G) {
    int z = item >= tot0;
    int loc = z ? item - tot0 : item;
    int my = loc / nx, nxi = loc - my * nx;
    gemm_tile(z ? p.A1 : p.A0, z ? p.Wh1 : p.Wh0, z ? p.Wl1 : p.Wl0,
              z ? p.b1 : p.b0, p.ldB, z ? p.C1 : p.C0, p.ldC,
              p.K, p.Kp, p.N, p.act, my * 32, nxi * 64, Ah, Al, Bh, Bl);
  }
}

__device__ void run_nei(const FusedArgs& fa, int bid, int G)
{
  for (int node = bid; node < Mres + Mrg; node += G) {
    const float *Ra, *Rb; const int *ag, *bg, *nnb; float* out; int Nn, loc;
    if (node < Mres) { Ra=fa.RaU1_r; Rb=fa.Rb_r; ag=fa.res_ag; bg=fa.res_bg;
                       nnb=fa.res_nnb; out=fa.nei_r; Nn=cNR; loc=node; }
    else             { Ra=fa.RaU1_g; Rb=fa.Rb_g; ag=fa.rg_ag; bg=fa.rg_bg;
                       nnb=fa.rg_nnb; out=fa.nei_g; Nn=cNG; loc=node-Mres; }
    int nn = nnb[loc];
    const int* agp = ag + (size_t)loc * cMAXNB * 2;
    const int* bgp = bg + (size_t)loc * cMAXNB * 2;
    for (int h = threadIdx.x; h < cH; h += 256) {
      float s = 0.f;
      for (int k = 0; k < nn; ++k) {
        int ra = agp[2 * k] * Nn + agp[2 * k + 1];
        int rb = bgp[2 * k] * Nn + bgp[2 * k + 1];
        s += fmaxf(Ra[(size_t)ra * 600 + h] + Rb[(size_t)rb * cH + h], 0.f);
      }
      out[(size_t)loc * cH + h] = s;
    }
  }
}

__device__ void run_kernels2(const FusedArgs& fa, int bid, int G)
{
  for (int node = bid; node < Mres + Mrg; node += G) {
    const float *SaSe, *Sb, *mk; const int *ag, *bg, *nnb; float* out; int Nn, loc;
    if (node < Mres) { SaSe=fa.RaU1_r; Sb=fa.Sb_r; ag=fa.res_ag; bg=fa.res_bg;
                       nnb=fa.res_nnb; mk=fa.res_mask; out=fa.kern_r; Nn=cNR; loc=node; }
    else             { SaSe=fa.RaU1_g; Sb=fa.Sb_g; ag=fa.rg_ag; bg=fa.rg_bg;
                       nnb=fa.rg_nnb; mk=fa.rg_mask; out=fa.kern_g; Nn=cNG; loc=node-Mres; }
    int nn = nnb[loc];
    const int* agp = ag + (size_t)loc * cMAXNB * 2;
    const int* bgp = bg + (size_t)loc * cMAXNB * 2;
    for (int h = threadIdx.x; h < cH; h += 256) {
      float s = 0.f;
      for (int k = 0; k < nn; ++k) {
        int ra = agp[2 * k] * Nn + agp[2 * k + 1];
        int rb = bgp[2 * k] * Nn + bgp[2 * k + 1];
        s += SaSe[(size_t)ra * 600 + h] * Sb[(size_t)rb * cH + h];
      }
      out[(size_t)loc * cH + h] = s * SaSe[(size_t)loc * 600 + 300 + h] * mk[loc];
    }
  }
}

__global__ __launch_bounds__(256, 4) void wln_fused(FusedArgs fa)
{
  __shared__ unsigned short Ah[2][32][40];
  __shared__ unsigned short Al[2][32][40];
  __shared__ unsigned short Bh[2][64][40];
  __shared__ unsigned short Bl[2][64][40];
  cg::grid_group grid = cg::this_grid();
  int bid = blockIdx.x, G = gridDim.x;

  for (int it = 0; it < cDEPTH - 1; ++it) {
    float* af_r = (it & 1) ? fa.afB_r : fa.afA_r;
    float* af_g = (it & 1) ? fa.afB_g : fa.afA_g;
    float* afo_r = (it & 1) ? fa.afA_r : fa.afB_r;
    float* afo_g = (it & 1) ? fa.afA_g : fa.afB_g;

    GemmP p1;
    p1.A0 = af_r; p1.A1 = af_g;
    p1.Wh0 = fa.cat1_h0; p1.Wl0 = fa.cat1_l0; p1.Wh1 = fa.cat1_h1; p1.Wl1 = fa.cat1_l1;
    p1.b0 = nullptr; p1.b1 = nullptr; p1.ldB = 0;
    p1.C0 = fa.RaU1_r; p1.C1 = fa.RaU1_g; p1.ldC = 600;
    p1.K = cH; p1.Kp = 320; p1.N = 600; p1.act = 0;
    run_gemm(p1, bid, G, Ah, Al, Bh, Bl);
    grid.sync();

    run_nei(fa, bid, G);
    grid.sync();

    GemmP p2;
    p2.A0 = fa.nei_r; p2.A1 = fa.nei_g;
    p2.Wh0 = fa.U1b_h0; p2.Wl0 = fa.U1b_l0; p2.Wh1 = fa.U1b_h1; p2.Wl1 = fa.U1b_l1;
    p2.b0 = fa.RaU1_r + 300; p2.b1 = fa.RaU1_g + 300; p2.ldB = 600;
    p2.C0 = afo_r; p2.C1 = afo_g; p2.ldC = cH;
    p2.K = cH; p2.Kp = 320; p2.N = cH; p2.act = 1;
    run_gemm(p2, bid, G, Ah, Al, Bh, Bl);
    grid.sync();
  }

  GemmP p3;
  p3.A0 = fa.afB_r; p3.A1 = fa.afB_g;
  p3.Wh0 = fa.cat2_h0; p3.Wl0 = fa.cat2_l0; p3.Wh1 = fa.cat2_h1; p3.Wl1 = fa.cat2_l1;
  p3.b0 = nullptr; p3.b1 = nullptr; p3.ldB = 0;
  p3.C0 = fa.RaU1_r; p3.C1 = fa.RaU1_g; p3.ldC = 600;
  p3.K = cH; p3.Kp = 320; p3.N = 600; p3.act = 1;
  run_gemm(p3, bid, G, Ah, Al, Bh, Bl);
  grid.sync();

  run_kernels2(fa, bid, G);
  grid.sync();

  GemmP p4;
  p4.A0 = fa.kern_r; p4.A1 = fa.kern_g;
  p4.Wh0 = fa.att_h; p4.Wl0 = fa.att_l; p4.Wh1 = fa.att_h; p4.Wl1 = fa.att_l;
  p4.b0 = nullptr; p4.b1 = nullptr; p4.ldB = 0;
  p4.C0 = fa.U; p4.C1 = fa.V; p4.ldC = cH;
  p4.K = cH; p4.Kp = 320; p4.N = cH; p4.act = 0;
  run_gemm(p4, bid, G, Ah, Al, Bh, Bl);
}

// ---------------- fallback standalone gather kernels (round 9 verified) -----
__global__ __launch_bounds__(320) void nei_label2_k(
    const float* __restrict__ RaR, const float* __restrict__ RbR,
    const int* __restrict__ agR, const int* __restrict__ bgR,
    const int* __restrict__ nnbR, float* __restrict__ outR,
    const float* __restrict__ RaG, const float* __restrict__ RbG,
    const int* __restrict__ agG, const int* __restrict__ bgG,
    const int* __restrict__ nnbG, float* __restrict__ outG,
    int ldRa)
{
  int node = blockIdx.x;
  const float *Ra, *Rb; const int *ag, *bg, *nnb; float* out; int Nn, loc;
  if (node < Mres) { Ra=RaR; Rb=RbR; ag=agR; bg=bgR; nnb=nnbR; out=outR; Nn=cNR; loc=node; }
  else { Ra=RaG; Rb=RbG; ag=agG; bg=bgG; nnb=nnbG; out=outG; Nn=cNG; loc=node-Mres; }
  int h = threadIdx.x;
  int nn = nnb[loc];
  const int* agp = ag + (size_t)loc * cMAXNB * 2;
  const int* bgp = bg + (size_t)loc * cMAXNB * 2;
  if (h < cH) {
    float s = 0.f;
    for (int k = 0; k < nn; ++k) {
      int ra = agp[2 * k] * Nn + agp[2 * k + 1];
      int rb = bgp[2 * k] * Nn + bgp[2 * k + 1];
      s += fmaxf(Ra[(size_t)ra * ldRa + h] + Rb[(size_t)rb * cH + h], 0.f);
    }
    out[(size_t)loc * cH + h] = s;
  }
}

__global__ __launch_bounds__(320) void kernels2_k(
    const float* __restrict__ SaSeR, const float* __restrict__ SbR,
    const int* __restrict__ agR, const int* __restrict__ bgR,
    const int* __restrict__ nnbR, const float* __restrict__ maskR,
    float* __restrict__ outR,
    const float* __restrict__ SaSeG, const float* __restrict__ SbG,
    const int* __restrict__ agG, const int* __restrict__ bgG,
    const int* __restrict__ nnbG, const float* __restrict__ maskG,
    float* __restrict__ outG)
{
  int node = blockIdx.x;
  const float *SaSe, *Sb, *mk; const int *ag, *bg, *nnb; float* out; int Nn, loc;
  if (node < Mres) { SaSe=SaSeR; Sb=SbR; ag=agR; bg=bgR; nnb=nnbR; mk=maskR; out=outR; Nn=cNR; loc=node; }
  else { SaSe=SaSeG; Sb=SbG; ag=agG; bg=bgG; nnb=nnbG; mk=maskG; out=outG; Nn=cNG; loc=node-Mres; }
  int h = threadIdx.x;
  int nn = nnb[loc];
  const int* agp = ag + (size_t)loc * cMAXNB * 2;
  const int* bgp = bg + (size_t)loc * cMAXNB * 2;
  if (h < cH) {
    float s = 0.f;
    for (int k = 0; k < nn; ++k) {
      int ra = agp[2 * k] * Nn + agp[2 * k + 1];
      int rb = bgp[2 * k] * Nn + bgp[2 * k + 1];
      s += SaSe[(size_t)ra * 600 + h] * Sb[(size_t)rb * cH + h];
    }
    out[(size_t)loc * cH + h] = s * SaSe[(size_t)loc * 600 + 300 + h] * mk[loc];
  }
}

// ---------------- score GEMM + pairsum (round 9 verified) -------------------
__global__ __launch_bounds__(256) void score_mfma_k(
    const float* __restrict__ h, const float* __restrict__ conn,
    const int* __restrict__ cm,
    const unsigned short* __restrict__ W0h, const unsigned short* __restrict__ W0l,
    const float* __restrict__ Wsc, float* __restrict__ pairsum)
{
  const int Kp = 800;
  const int nT = Kp >> 5;
  int m0 = blockIdx.y * 64;
  int n0 = blockIdx.x * 64;

  __shared__ unsigned short Ah[2][64][40];
  __shared__ unsigned short Al[2][64][40];
  __shared__ unsigned short Bh[2][64][40];
  __shared__ unsigned short Bl[2][64][40];

  int tid = threadIdx.x;
  int sm = tid >> 2;
  int sk = (tid & 3) << 3;

  int p = m0 + sm;
  int s3 = cm[p * 3 + 0];
  const float* h1 = h + (size_t)(s3 * cNR + cm[p * 3 + 1]) * cF;
  const float* h2 = h + (size_t)(s3 * cNR + cm[p * 3 + 2]) * cF;
  const float* cp = conn + (size_t)p * 10;

  float areg[8];
  uint4 bh_reg, bl_reg;

  auto fetch = [&](int kv0) {
    int kv = kv0 + sk;
    if (kv + 7 < cF) {
      float4 u = *(const float4*)(h1 + kv);
      float4 v = *(const float4*)(h2 + kv);
      float4 u2 = *(const float4*)(h1 + kv + 4);
      float4 v2 = *(const float4*)(h2 + kv + 4);
      areg[0]=u.x+v.x; areg[1]=u.y+v.y; areg[2]=u.z+v.z; areg[3]=u.w+v.w;
      areg[4]=u2.x+v2.x; areg[5]=u2.y+v2.y; areg[6]=u2.z+v2.z; areg[7]=u2.w+v2.w;
    } else {
#pragma unroll
      for (int j = 0; j < 8; ++j) {
        int k = kv + j;
        float v = 0.f;
        if (k < cF) v = h1[k] + h2[k];
        else if (k < cD0) v = cp[k - cF];
        areg[j] = v;
      }
    }
    int gn = n0 + sm;
    if (gn < cD0) {
      size_t o = (size_t)gn * Kp + kv;
      bh_reg = *(const uint4*)(W0h + o);
      bl_reg = *(const uint4*)(W0l + o);
    } else {
      bh_reg = make_uint4(0,0,0,0); bl_reg = make_uint4(0,0,0,0);
    }
  };

  auto store = [&](int buf) {
    unsigned hs[8], ls[8];
#pragma unroll
    for (int j = 0; j < 8; ++j) {
      unsigned short hv = f2bf(areg[j]);
      hs[j] = hv;
      ls[j] = f2bf(areg[j] - bf2f(hv));
    }
    uint4 hh, ll;
    hh.x = hs[0] | (hs[1] << 16); hh.y = hs[2] | (hs[3] << 16);
    hh.z = hs[4] | (hs[5] << 16); hh.w = hs[6] | (hs[7] << 16);
    ll.x = ls[0] | (ls[1] << 16); ll.y = ls[2] | (ls[3] << 16);
    ll.z = ls[4] | (ls[5] << 16); ll.w = ls[6] | (ls[7] << 16);
    *(uint4*)&Ah[buf][sm][sk] = hh;
    *(uint4*)&Al[buf][sm][sk] = ll;
    *(uint4*)&Bh[buf][sm][sk] = bh_reg;
    *(uint4*)&Bl[buf][sm][sk] = bl_reg;
  };

  int l = tid & 63, w = tid >> 6;
  int wm = (w >> 1) << 5, wn = (w & 1) << 5;
  int ar = wm + (l & 15), br = wn + (l & 15);
  int kc = (l >> 4) << 3;

  v4f acc00 = {0,0,0,0}, acc01 = {0,0,0,0}, acc10 = {0,0,0,0}, acc11 = {0,0,0,0};

  fetch(0); store(0); __syncthreads();
  for (int t = 0; t < nT; ++t) {
    if (t + 1 < nT) fetch((t + 1) << 5);
    int cur = t & 1;
    v8s ah0 = *(const v8s*)&Ah[cur][ar][kc];
    v8s ah1 = *(const v8s*)&Ah[cur][ar + 16][kc];
    v8s al0 = *(const v8s*)&Al[cur][ar][kc];
    v8s al1 = *(const v8s*)&Al[cur][ar + 16][kc];
    v8s bh0 = *(const v8s*)&Bh[cur][br][kc];
    v8s bh1 = *(const v8s*)&Bh[cur][br + 16][kc];
    v8s bl0 = *(const v8s*)&Bl[cur][br][kc];
    v8s bl1 = *(const v8s*)&Bl[cur][br + 16][kc];
    acc00 = MFMA(ah0, bh0, acc00, 0, 0, 0);
    acc00 = MFMA(ah0, bl0, acc00, 0, 0, 0);
    acc00 = MFMA(al0, bh0, acc00, 0, 0, 0);
    acc01 = MFMA(ah0, bh1, acc01, 0, 0, 0);
    acc01 = MFMA(ah0, bl1, acc01, 0, 0, 0);
    acc01 = MFMA(al0, bh1, acc01, 0, 0, 0);
    acc10 = MFMA(ah1, bh0, acc10, 0, 0, 0);
    acc10 = MFMA(ah1, bl0, acc10, 0, 0, 0);
    acc10 = MFMA(al1, bh0, acc10, 0, 0, 0);
    acc11 = MFMA(ah1, bh1, acc11, 0, 0, 0);
    acc11 = MFMA(ah1, bl1, acc11, 0, 0, 0);
    acc11 = MFMA(al1, bh1, acc11, 0, 0, 0);
    if (t + 1 < nT) store(cur ^ 1);
    __syncthreads();
  }

  int cbase = n0 + wn + (l & 15);
  float w0 = (cbase      < cD0) ? Wsc[cbase]      : 0.f;
  float w1 = (cbase + 16 < cD0) ? Wsc[cbase + 16] : 0.f;
  float ps[8];
#pragma unroll
  for (int r = 0; r < 4; ++r) {
    ps[r]     = fmaxf(acc00[r], 0.f) * w0 + fmaxf(acc01[r], 0.f) * w1;
    ps[4 + r] = fmaxf(acc10[r], 0.f) * w0 + fmaxf(acc11[r], 0.f) * w1;
  }
#pragma unroll
  for (int m = 1; m < 16; m <<= 1) {
#pragma unroll
    for (int q = 0; q < 8; ++q) ps[q] += __shfl_xor(ps[q], m, 64);
  }
  if ((l & 15) == 0) {
#pragma unroll
    for (int q = 0; q < 8; ++q) {
      int gm = m0 + wm + (q >> 2) * 16 + ((l >> 4) << 2) + (q & 3);
      atomicAdd(&pairsum[gm], ps[q]);
    }
  }
}

// ---------------- attention + ctx + h assembly (round-6 verified) -----------
#define AIT 4
__global__ __launch_bounds__(256) void att_ctx_h_k(
    const float* __restrict__ U, const float* __restrict__ V,
    const float* __restrict__ att_w, const float* __restrict__ rgh,
    const float* __restrict__ kern, const float* __restrict__ qm,
    float* __restrict__ h)
{
  __shared__ float attL[AIT][cNG];
  int blk = blockIdx.x;
  int b = blk / (cNR / AIT);
  int it = blk - b * (cNR / AIT);
  int row0 = b * cNR + it * AIT;
  int tid = threadIdx.x, lane = tid & 63, w = tid >> 6;
  int n0 = lane * 4, n1 = 256 + lane * 4;
  bool v1 = (lane < 11);
  float4 z4 = make_float4(0.f, 0.f, 0.f, 0.f);

  float4 u[AIT][2], wv[2];
  wv[0] = *(const float4*)(att_w + n0);
  wv[1] = v1 ? *(const float4*)(att_w + n1) : z4;
#pragma unroll
  for (int i = 0; i < AIT; ++i) {
    const float* Ur = U + (size_t)(row0 + i) * cH;
    u[i][0] = *(const float4*)(Ur + n0);
    u[i][1] = v1 ? *(const float4*)(Ur + n1) : z4;
  }

  for (int r = 0; r < 4; ++r) {
    int jb = w * 16 + r * 4;
    float4 vv[4][2];
#pragma unroll
    for (int q = 0; q < 4; ++q) {
      const float* Vr = V + (size_t)(b * cNG + jb + q) * cH;
      vv[q][0] = *(const float4*)(Vr + n0);
      vv[q][1] = v1 ? *(const float4*)(Vr + n1) : z4;
    }
    float s[4][AIT];
#pragma unroll
    for (int q = 0; q < 4; ++q)
#pragma unroll
      for (int i = 0; i < AIT; ++i) {
        float acc = 0.f;
#pragma unroll
        for (int pp = 0; pp < 2; ++pp) {
          float4 uu = u[i][pp], vq = vv[q][pp], ww = wv[pp];
          acc += fmaxf(uu.x + vq.x, 0.f) * ww.x;
          acc += fmaxf(uu.y + vq.y, 0.f) * ww.y;
          acc += fmaxf(uu.z + vq.z, 0.f) * ww.z;
          acc += fmaxf(uu.w + vq.w, 0.f) * ww.w;
        }
        s[q][i] = acc;
      }
#pragma unroll
    for (int m = 1; m < 64; m <<= 1)
#pragma unroll
      for (int q = 0; q < 4; ++q)
#pragma unroll
        for (int i = 0; i < AIT; ++i)
          s[q][i] += __shfl_xor(s[q][i], m);
    if (lane < 16) {
      float sv = 0.f;
#pragma unroll
      for (int q = 0; q < 4; ++q)
#pragma unroll
        for (int i = 0; i < AIT; ++i)
          if (lane == q * 4 + i) sv = s[q][i];
      attL[lane & 3][jb + (lane >> 2)] = 1.f / (1.f + expf(-sv));
    }
  }
  __syncthreads();

  const float* rgb = rgh + (size_t)b * cNG * cH;
  float* hrow = h + (size_t)(row0 + w) * cF;
  for (int c = lane; c < 75; c += 64) {
    float4 p = z4;
    for (int j = 0; j < cNG; ++j) {
      float aj = attL[w][j];
      float4 rv = *(const float4*)(rgb + (size_t)j * cH + c * 4);
      p.x += aj * rv.x; p.y += aj * rv.y; p.z += aj * rv.z; p.w += aj * rv.w;
    }
    *(float4*)(hrow + cH + c * 4) = p;
  }
  for (int idx = tid; idx < AIT * 75; idx += 256) {
    int i = idx / 75, c = idx - i * 75;
    *(float4*)(h + (size_t)(row0 + i) * cF + c * 4) =
        *(const float4*)(kern + (size_t)(row0 + i) * cH + c * 4);
  }
  for (int idx = tid; idx < AIT * 40; idx += 256) {
    int i = idx / 40, c = idx - i * 40;
    *(float4*)(h + (size_t)(row0 + i) * cF + 2 * cH + c * 4) =
        *(const float4*)(qm + (size_t)(row0 + i) * cQM + c * 4);
  }
}

__global__ void seg_final_k(const float* __restrict__ ps,
                            const int* __restrict__ cm, float* __restrict__ out)
{
  __shared__ float s[cB];
  int tid = threadIdx.x;
  if (tid < cB) s[tid] = 0.f;
  __syncthreads();
  for (int p = tid; p < cP; p += 256) atomicAdd(&s[cm[p * 3]], ps[p]);
  __syncthreads();
  if (tid < cB) out[tid] = s[tid] * (1.f / 128.f);
}

// ---------------------------------------------------------------------------
extern "C" void kernel_launch(void* const* d_in, const int* in_sizes, int n_in,
                              void* d_out, int out_size, void* d_ws, size_t ws_size,
                              hipStream_t stream)
{
  (void)in_sizes; (void)n_in; (void)out_size; (void)ws_size;
  const float* res_atom = (const float*)d_in[0];
  const float* res_bond = (const float*)d_in[1];
  const int*   res_ag   = (const int*)d_in[2];
  const int*   res_bg   = (const int*)d_in[3];
  const int*   res_nnb  = (const int*)d_in[4];
  const float* res_mask = (const float*)d_in[5];
  const float* rg_atom  = (const float*)d_in[6];
  const float* rg_bond  = (const float*)d_in[7];
  const int*   rg_ag    = (const int*)d_in[8];
  const int*   rg_bg    = (const int*)d_in[9];
  const int*   rg_nnb   = (const int*)d_in[10];
  const float* rg_mask  = (const float*)d_in[11];
  const int*   core     = (const int*)d_in[12];
  const float* qm       = (const float*)d_in[13];
  const float* connect  = (const float*)d_in[14];
  const float* Wm[2][6];
  for (int s = 0; s < 2; ++s)
    for (int k = 0; k < 6; ++k) Wm[s][k] = (const float*)d_in[15 + s * 6 + k];
  const float* W_att_h  = (const float*)d_in[27];
  const float* W_att_s  = (const float*)d_in[28];
  const float* W_score0 = (const float*)d_in[29];
  const float* W_score  = (const float*)d_in[30];
  float* out = (float*)d_out;

  float* ws = (float*)d_ws;
  size_t off = 0;
  auto alloc = [&](size_t nfloat) {
    float* p = ws + off;
    off += (nfloat + 63) & ~(size_t)63;
    return p;
  };
  auto allocU = [&](size_t nush) {
    return (unsigned short*)alloc((nush + 1) / 2);
  };

  float* afA_r  = alloc((size_t)Mres * cH);
  float* afB_r  = alloc((size_t)Mres * cH);
  float* Rb_r   = alloc((size_t)Mres * cH);
  float* Sb_r   = alloc((size_t)Mres * cH);
  float* RaU1_r = alloc((size_t)Mres * 600);
  float* nei_r  = alloc((size_t)Mres * cH);
  float* kern_r = alloc((size_t)Mres * cH);
  float* afA_g  = alloc((size_t)Mrg * cH);
  float* afB_g  = alloc((size_t)Mrg * cH);
  float* Rb_g   = alloc((size_t)Mrg * cH);
  float* Sb_g   = alloc((size_t)Mrg * cH);
  float* RaU1_g = alloc((size_t)Mrg * 600);
  float* nei_g  = alloc((size_t)Mrg * cH);
  float* kern_g = alloc((size_t)Mrg * cH);
  float* U      = alloc((size_t)Mres * cH);
  float* V      = alloc((size_t)Mrg * cH);
  float* h760   = alloc((size_t)Mres * cF);
  float* pairsum = alloc(cP);

  unsigned short *atomT_h[2], *atomT_l[2], *nbT_h[2], *nbT_l[2];
  unsigned short *U2bT_h[2], *U2bT_l[2], *cat1_h[2], *cat1_l[2];
  unsigned short *cat2_h[2], *cat2_l[2], *U1bT_h[2], *U1bT_l[2];
  for (int s = 0; s < 2; ++s) {
    atomT_h[s] = allocU((size_t)300 * 128); atomT_l[s] = allocU((size_t)300 * 128);
    nbT_h[s]   = allocU((size_t)300 * 32);  nbT_l[s]   = allocU((size_t)300 * 32);
    U2bT_h[s]  = allocU((size_t)300 * 32);  U2bT_l[s]  = allocU((size_t)300 * 32);
    cat1_h[s]  = allocU((size_t)600 * 320); cat1_l[s]  = allocU((size_t)600 * 320);
    cat2_h[s]  = allocU((size_t)600 * 320); cat2_l[s]  = allocU((size_t)600 * 320);
    U1bT_h[s]  = allocU((size_t)300 * 320); U1bT_l[s]  = allocU((size_t)300 * 320);
  }
  unsigned short* attT_h = allocU((size_t)300 * 320);
  unsigned short* attT_l = allocU((size_t)300 * 320);
  unsigned short* sc0T_h = allocU((size_t)770 * 800);
  unsigned short* sc0T_l = allocU((size_t)770 * 800);

  // ---- prep (18 transposes + pairsum zero)
  {
    PrepArgs pa{};
    int e = 0, base = 0;
    auto add = [&](const float* W, unsigned short* ht, unsigned short* lt,
                   int K, int N, int Kp) {
      pa.e[e] = {W, ht, lt, K, N, Kp};
      pa.bases[e] = base;
      base += N * Kp;
      ++e;
    };
    for (int s = 0; s < 2; ++s) {
      add(Wm[s][0], atomT_h[s], atomT_l[s], cAF, cH, 128);
      add(Wm[s][2], nbT_h[s],   nbT_l[s],   cBF, cH, 32);
      add(Wm[s][4] + (size_t)cH * cH, U2bT_h[s], U2bT_l[s], cBF, cH, 32);
      add(Wm[s][4], cat1_h[s],               cat1_l[s],               cH, cH, 320);
      add(Wm[s][5], cat1_h[s] + 300 * 320,   cat1_l[s] + 300 * 320,   cH, cH, 320);
      add(Wm[s][1], cat2_h[s],               cat2_l[s],               cH, cH, 320);
      add(Wm[s][3], cat2_h[s] + 300 * 320,   cat2_l[s] + 300 * 320,   cH, cH, 320);
      add(Wm[s][5] + (size_t)cH * cH, U1bT_h[s], U1bT_l[s], cH, cH, 320);
    }
    add(W_att_h,  attT_h, attT_l, cH, cH, 320);
    add(W_score0, sc0T_h, sc0T_l, cD0, cD0, 800);
    pa.e[e] = {nullptr, (unsigned short*)pairsum, nullptr, 0, 0, 0};
    pa.bases[e] = base; base += cP; ++e;
    pa.bases[e] = base;
    pa.nent = e;
    prep_k<<<dim3((base + 255) / 256), dim3(256), 0, stream>>>(pa);
  }

  dim3 blk(256);
  auto gplain = [&](const float* A, const unsigned short* Wh, const unsigned short* Wl,
                    float* C, int ldC, int M, int K, int Kp, int act,
                    const float* bias = nullptr, int ldb = 0) {
    GArg g{};
    g.A = A; g.Wh = Wh; g.Wl = Wl; g.bias = bias; g.ldBias = ldb;
    g.C = C; g.ldC = ldC; g.M = M; g.K = K; g.Kp = Kp; g.act = act;
    return g;
  };
  GArg zero{};

  // prologue: af0=relu(atom@W_atom); Rb=bond@U2b; Sb=relu(bond@W_nb)
  {
    GArgs6 ga{{
      gplain(res_atom, atomT_h[0], atomT_l[0], afA_r, cH, Mres, cAF, 128, 1),
      gplain(rg_atom,  atomT_h[1], atomT_l[1], afA_g, cH, Mrg,  cAF, 128, 1),
      gplain(res_bond, U2bT_h[0],  U2bT_l[0],  Rb_r,  cH, Mres, cBF, 32, 0),
      gplain(rg_bond,  U2bT_h[1],  U2bT_l[1],  Rb_g,  cH, Mrg,  cBF, 32, 0),
      gplain(res_bond, nbT_h[0],   nbT_l[0],   Sb_r,  cH, Mres, cBF, 32, 1),
      gplain(rg_bond,  nbT_h[1],   nbT_l[1],   Sb_g,  cH, Mrg,  cBF, 32, 1),
    }};
    gemm32<<<dim3(5, Mres / 32, 6), blk, 0, stream>>>(ga, cH);
  }

  // fused WLN (cooperative, occupancy-sized) with checked fallback
  bool coop_ok = false;
  {
    FusedArgs fa{};
    fa.afA_r = afA_r; fa.afB_r = afB_r; fa.afA_g = afA_g; fa.afB_g = afB_g;
    fa.Rb_r = Rb_r; fa.Rb_g = Rb_g; fa.Sb_r = Sb_r; fa.Sb_g = Sb_g;
    fa.RaU1_r = RaU1_r; fa.RaU1_g = RaU1_g;
    fa.nei_r = nei_r; fa.nei_g = nei_g;
    fa.kern_r = kern_r; fa.kern_g = kern_g;
    fa.U = U; fa.V = V;
    fa.cat1_h0 = cat1_h[0]; fa.cat1_l0 = cat1_l[0];
    fa.cat1_h1 = cat1_h[1]; fa.cat1_l1 = cat1_l[1];
    fa.U1b_h0 = U1bT_h[0]; fa.U1b_l0 = U1bT_l[0];
    fa.U1b_h1 = U1bT_h[1]; fa.U1b_l1 = U1bT_l[1];
    fa.cat2_h0 = cat2_h[0]; fa.cat2_l0 = cat2_l[0];
    fa.cat2_h1 = cat2_h[1]; fa.cat2_l1 = cat2_l[1];
    fa.att_h = attT_h; fa.att_l = attT_l;
    fa.res_ag = res_ag; fa.res_bg = res_bg; fa.res_nnb = res_nnb;
    fa.rg_ag = rg_ag; fa.rg_bg = rg_bg; fa.rg_nnb = rg_nnb;
    fa.res_mask = res_mask; fa.rg_mask = rg_mask;

    int maxBlk = 0;
    hipError_t oe = hipOccupancyMaxActiveBlocksPerMultiprocessor(
        &maxBlk, wln_fused, 256, 0);
    if (oe == hipSuccess && maxBlk > 0) {
      int grid = maxBlk * 256;
      if (grid > 768) grid = 768;
      void* args[] = {(void*)&fa};
      hipError_t ce = hipLaunchCooperativeKernel(
          (const void*)wln_fused, dim3(grid), blk, args, 0, stream);
      coop_ok = (ce == hipSuccess);
    }
  }

  if (!coop_ok) {
    // ---- round-9 verified fallback sequence
    const int MT = Mres / 32;
    float* af_r = afA_r; float* afo_r = afB_r;
    float* af_g = afA_g; float* afo_g = afB_g;
    for (int it = 0; it < cDEPTH - 1; ++it) {
      {
        GArgs6 ga{{
          gplain(af_r, cat1_h[0], cat1_l[0], RaU1_r, 600, Mres, cH, 320, 0),
          gplain(af_g, cat1_h[1], cat1_l[1], RaU1_g, 600, Mrg,  cH, 320, 0),
          zero, zero, zero, zero,
        }};
        gemm32<<<dim3(10, MT, 2), blk, 0, stream>>>(ga, 600);
      }
      nei_label2_k<<<dim3(Mres + Mrg), dim3(320), 0, stream>>>(
          RaU1_r, Rb_r, res_ag, res_bg, res_nnb, nei_r,
          RaU1_g, Rb_g, rg_ag, rg_bg, rg_nnb, nei_g, 600);
      {
        GArgs6 ga{{
          gplain(nei_r, U1bT_h[0], U1bT_l[0], afo_r, cH, Mres, cH, 320, 1,
                 RaU1_r + 300, 600),
          gplain(nei_g, U1bT_h[1], U1bT_l[1], afo_g, cH, Mrg, cH, 320, 1,
                 RaU1_g + 300, 600),
          zero, zero, zero, zero,
        }};
        gemm32<<<dim3(5, MT, 2), blk, 0, stream>>>(ga, cH);
      }
      { float* tmp = af_r; af_r = afo_r; afo_r = tmp; }
      { float* tmp = af_g; af_g = afo_g; afo_g = tmp; }
    }
    {
      GArgs6 ga{{
        gplain(af_r, cat2_h[0], cat2_l[0], RaU1_r, 600, Mres, cH, 320, 1),
        gplain(af_g, cat2_h[1], cat2_l[1], RaU1_g, 600, Mrg,  cH, 320, 1),
        zero, zero, zero, zero,
      }};
      gemm32<<<dim3(10, MT, 2), blk, 0, stream>>>(ga, 600);
    }
    kernels2_k<<<dim3(Mres + Mrg), dim3(320), 0, stream>>>(
        RaU1_r, Sb_r, res_ag, res_bg, res_nnb, res_mask, kern_r,
        RaU1_g, Sb_g, rg_ag, rg_bg, rg_nnb, rg_mask, kern_g);
    {
      GArgs6 ga{{
        gplain(kern_r, attT_h, attT_l, U, cH, Mres, cH, 320, 0),
        gplain(kern_g, attT_h, attT_l, V, cH, Mrg,  cH, 320, 0),
        zero, zero, zero, zero,
      }};
      gemm32<<<dim3(5, MT, 2), blk, 0, stream>>>(ga, cH);
    }
  }

  att_ctx_h_k<<<dim3(cB * (cNR / AIT)), dim3(256), 0, stream>>>(
      U, V, W_att_s, kern_g, kern_r, qm, h760);

  score_mfma_k<<<dim3(13, cP / 64), blk, 0, stream>>>(
      h760, connect, core, sc0T_h, sc0T_l, W_score, pairsum);
  seg_final_k<<<dim3(1), dim3(256), 0, stream>>>(pairsum, core, out);
}

// Round 12
// 241.924 us; speedup vs baseline: 4.2945x; 4.2945x over previous
//
#include <hip/hip_runtime.h>

// ---------------------------------------------------------------------------
// QMWLNPairwiseAtomClassifier — round 12 (= round 9 + score->out fusion):
//  * verified round-9 dispatch structure (coop fusion reverted: grid.sync on
//    8-XCD flushes L2 per sync -> 170MB refetch, 1.2ms; measured round 11)
//  * score_mfma epilogue: block-reduce + 1 atomicAdd directly into d_out
//    (seg_final + pairsum deleted; prep zeroes out[16])
// ---------------------------------------------------------------------------

constexpr int cB = 16, cNR = 96, cNG = 64;
constexpr int cAF = 98, cBF = 6;
constexpr int cH = 300, cQM = 160, cMAXNB = 10, cDEPTH = 4;
constexpr int cP = 2048;
constexpr int cF = 2 * cH + cQM;   // 760
constexpr int cD0 = cF + 10;       // 770

constexpr int Mres = cB * cNR;     // 1536
constexpr int Mrg  = cB * cNG;     // 1024

typedef __attribute__((ext_vector_type(8))) short v8s;
typedef __attribute__((ext_vector_type(4))) float v4f;

__device__ inline unsigned short f2bf(float f) {
  unsigned u = __float_as_uint(f);
  u += 0x7FFF + ((u >> 16) & 1);          // RNE
  return (unsigned short)(u >> 16);
}
__device__ inline float bf2f(unsigned short s) {
  return __uint_as_float(((unsigned)s) << 16);
}

// ---------------- prep: transpose+split all weights, zero out[16] -----------
struct PrepEnt { const float* W; unsigned short* hiT; unsigned short* loT;
                 int K, N, Kpad; };
struct PrepArgs { PrepEnt e[19]; int bases[20]; int nent; };

__global__ __launch_bounds__(256) void prep_k(PrepArgs pa)
{
  int g = blockIdx.x * 256 + threadIdx.x;
  if (g >= pa.bases[pa.nent]) return;
  int idx = 0;
  while (g >= pa.bases[idx + 1]) ++idx;
  PrepEnt p = pa.e[idx];
  int local = g - pa.bases[idx];
  if (!p.W) { ((float*)p.hiT)[local] = 0.f; return; }
  int n = local / p.Kpad, k = local - n * p.Kpad;
  float w = (k < p.K) ? p.W[(size_t)k * p.N + n] : 0.f;
  unsigned short h = f2bf(w);
  p.hiT[local] = h;
  p.loT[local] = f2bf(w - bf2f(h));
}

// ---------------- MFMA GEMM (BM=32): C = act(A@W + bias) --------------------
struct GArg {
  const float* A;                                      // M x K, ld=K
  const unsigned short* Wh; const unsigned short* Wl;  // [N][Kp]
  const float* bias; int ldBias;
  float* C; int ldC;
  int M, K, Kp, act;
};
struct GArgs6 { GArg a[6]; };

#define MFMA __builtin_amdgcn_mfma_f32_16x16x32_bf16

__global__ __launch_bounds__(256) void gemm32(GArgs6 ga, int N)
{
  GArg g = ga.a[blockIdx.z];
  int m0 = blockIdx.y * 32;
  if (m0 >= g.M) return;
  int n0 = blockIdx.x * 64;
  int nT = g.Kp >> 5;

  __shared__ unsigned short Ah[2][32][40];
  __shared__ unsigned short Al[2][32][40];
  __shared__ unsigned short Bh[2][64][40];
  __shared__ unsigned short Bl[2][64][40];

  int tid = threadIdx.x;
  bool doA = tid < 128;
  int smA = tid >> 2;           // 0..31 (valid when doA)
  int skA = (tid & 3) << 3;
  int smB = tid >> 2;           // 0..63
  int skB = (tid & 3) << 3;
  int gmA = m0 + smA;

  float areg[8];
  uint4 bh_reg, bl_reg;

  auto fetch = [&](int kv0) {
    if (doA) {
      int kk = kv0 + skA;
      const float* src = g.A + (size_t)gmA * g.K;
      if (((g.K & 3) == 0) && kk + 7 < g.K) {
        float4 v0 = *(const float4*)(src + kk);
        float4 v1 = *(const float4*)(src + kk + 4);
        areg[0]=v0.x; areg[1]=v0.y; areg[2]=v0.z; areg[3]=v0.w;
        areg[4]=v1.x; areg[5]=v1.y; areg[6]=v1.z; areg[7]=v1.w;
      } else {
#pragma unroll
        for (int j = 0; j < 8; ++j) areg[j] = (kk + j < g.K) ? src[kk + j] : 0.f;
      }
    }
    int gn = n0 + smB;
    int kkb = kv0 + skB;
    if (gn < N) {
      size_t o = (size_t)gn * g.Kp + kkb;
      bh_reg = *(const uint4*)(g.Wh + o);
      bl_reg = *(const uint4*)(g.Wl + o);
    } else {
      bh_reg = make_uint4(0,0,0,0); bl_reg = make_uint4(0,0,0,0);
    }
  };

  auto store = [&](int buf) {
    if (doA) {
      unsigned hs[8], ls[8];
#pragma unroll
      for (int j = 0; j < 8; ++j) {
        unsigned short hv = f2bf(areg[j]);
        hs[j] = hv;
        ls[j] = f2bf(areg[j] - bf2f(hv));
      }
      uint4 hh, ll;
      hh.x = hs[0] | (hs[1] << 16); hh.y = hs[2] | (hs[3] << 16);
      hh.z = hs[4] | (hs[5] << 16); hh.w = hs[6] | (hs[7] << 16);
      ll.x = ls[0] | (ls[1] << 16); ll.y = ls[2] | (ls[3] << 16);
      ll.z = ls[4] | (ls[5] << 16); ll.w = ls[6] | (ls[7] << 16);
      *(uint4*)&Ah[buf][smA][skA] = hh;
      *(uint4*)&Al[buf][smA][skA] = ll;
    }
    *(uint4*)&Bh[buf][smB][skB] = bh_reg;
    *(uint4*)&Bl[buf][smB][skB] = bl_reg;
  };

  int l = tid & 63, w = tid >> 6;
  int wr = (w >> 1) << 4;       // 0 / 16
  int wc = (w & 1) << 5;        // 0 / 32
  int arow = wr + (l & 15);
  int brow = wc + (l & 15);
  int kc = (l >> 4) << 3;

  v4f acc0 = {0,0,0,0}, acc1 = {0,0,0,0};

  fetch(0); store(0); __syncthreads();
  for (int t = 0; t < nT; ++t) {
    if (t + 1 < nT) fetch((t + 1) << 5);
    int cur = t & 1;
    v8s ah  = *(const v8s*)&Ah[cur][arow][kc];
    v8s al  = *(const v8s*)&Al[cur][arow][kc];
    v8s bh0 = *(const v8s*)&Bh[cur][brow][kc];
    v8s bh1 = *(const v8s*)&Bh[cur][brow + 16][kc];
    v8s bl0 = *(const v8s*)&Bl[cur][brow][kc];
    v8s bl1 = *(const v8s*)&Bl[cur][brow + 16][kc];
    acc0 = MFMA(ah, bh0, acc0, 0, 0, 0);
    acc0 = MFMA(ah, bl0, acc0, 0, 0, 0);
    acc0 = MFMA(al, bh0, acc0, 0, 0, 0);
    acc1 = MFMA(ah, bh1, acc1, 0, 0, 0);
    acc1 = MFMA(ah, bl1, acc1, 0, 0, 0);
    acc1 = MFMA(al, bh1, acc1, 0, 0, 0);
    if (t + 1 < nT) store(cur ^ 1);
    __syncthreads();
  }

  int rbase = m0 + wr + ((l >> 4) << 2);
  int cbase = n0 + wc + (l & 15);
  v4f accs[2] = {acc0, acc1};
#pragma unroll
  for (int fj = 0; fj < 2; ++fj) {
    int gn = cbase + fj * 16;
    if (gn >= N) continue;
    float* Cp = g.C + (size_t)rbase * g.ldC + gn;
    const float* Bp = g.bias ? g.bias + (size_t)rbase * g.ldBias + gn : nullptr;
#pragma unroll
    for (int r = 0; r < 4; ++r) {
      float v = accs[fj][r];
      if (Bp) v += Bp[(size_t)r * g.ldBias];
      if (g.act) v = fmaxf(v, 0.f);
      Cp[(size_t)r * g.ldC] = v;
    }
  }
}

// ---------------- score GEMM + fused rh·Wsc -> one atomicAdd into out -------
__global__ __launch_bounds__(256) void score_mfma_k(
    const float* __restrict__ h, const float* __restrict__ conn,
    const int* __restrict__ cm,
    const unsigned short* __restrict__ W0h, const unsigned short* __restrict__ W0l,
    const float* __restrict__ Wsc, float* __restrict__ outp)
{
  const int Kp = 800;
  const int nT = Kp >> 5;           // 25
  int m0 = blockIdx.y * 64;
  int n0 = blockIdx.x * 64;

  __shared__ unsigned short Ah[2][64][40];
  __shared__ unsigned short Al[2][64][40];
  __shared__ unsigned short Bh[2][64][40];
  __shared__ unsigned short Bl[2][64][40];
  __shared__ float red[16];

  int tid = threadIdx.x;
  int sm = tid >> 2;
  int sk = (tid & 3) << 3;

  int p = m0 + sm;
  int s3 = cm[p * 3 + 0];
  const float* h1 = h + (size_t)(s3 * cNR + cm[p * 3 + 1]) * cF;
  const float* h2 = h + (size_t)(s3 * cNR + cm[p * 3 + 2]) * cF;
  const float* cp = conn + (size_t)p * 10;

  float areg[8];
  uint4 bh_reg, bl_reg;

  auto fetch = [&](int kv0) {
    int kv = kv0 + sk;
    if (kv + 7 < cF) {
      float4 u = *(const float4*)(h1 + kv);
      float4 v = *(const float4*)(h2 + kv);
      float4 u2 = *(const float4*)(h1 + kv + 4);
      float4 v2 = *(const float4*)(h2 + kv + 4);
      areg[0]=u.x+v.x; areg[1]=u.y+v.y; areg[2]=u.z+v.z; areg[3]=u.w+v.w;
      areg[4]=u2.x+v2.x; areg[5]=u2.y+v2.y; areg[6]=u2.z+v2.z; areg[7]=u2.w+v2.w;
    } else {
#pragma unroll
      for (int j = 0; j < 8; ++j) {
        int k = kv + j;
        float v = 0.f;
        if (k < cF) v = h1[k] + h2[k];
        else if (k < cD0) v = cp[k - cF];
        areg[j] = v;
      }
    }
    int gn = n0 + sm;
    if (gn < cD0) {
      size_t o = (size_t)gn * Kp + kv;
      bh_reg = *(const uint4*)(W0h + o);
      bl_reg = *(const uint4*)(W0l + o);
    } else {
      bh_reg = make_uint4(0,0,0,0); bl_reg = make_uint4(0,0,0,0);
    }
  };

  auto store = [&](int buf) {
    unsigned hs[8], ls[8];
#pragma unroll
    for (int j = 0; j < 8; ++j) {
      unsigned short hv = f2bf(areg[j]);
      hs[j] = hv;
      ls[j] = f2bf(areg[j] - bf2f(hv));
    }
    uint4 hh, ll;
    hh.x = hs[0] | (hs[1] << 16); hh.y = hs[2] | (hs[3] << 16);
    hh.z = hs[4] | (hs[5] << 16); hh.w = hs[6] | (hs[7] << 16);
    ll.x = ls[0] | (ls[1] << 16); ll.y = ls[2] | (ls[3] << 16);
    ll.z = ls[4] | (ls[5] << 16); ll.w = ls[6] | (ls[7] << 16);
    *(uint4*)&Ah[buf][sm][sk] = hh;
    *(uint4*)&Al[buf][sm][sk] = ll;
    *(uint4*)&Bh[buf][sm][sk] = bh_reg;
    *(uint4*)&Bl[buf][sm][sk] = bl_reg;
  };

  int l = tid & 63, w = tid >> 6;
  int wm = (w >> 1) << 5, wn = (w & 1) << 5;
  int ar = wm + (l & 15), br = wn + (l & 15);
  int kc = (l >> 4) << 3;

  v4f acc00 = {0,0,0,0}, acc01 = {0,0,0,0}, acc10 = {0,0,0,0}, acc11 = {0,0,0,0};

  fetch(0); store(0); __syncthreads();
  for (int t = 0; t < nT; ++t) {
    if (t + 1 < nT) fetch((t + 1) << 5);
    int cur = t & 1;
    v8s ah0 = *(const v8s*)&Ah[cur][ar][kc];
    v8s ah1 = *(const v8s*)&Ah[cur][ar + 16][kc];
    v8s al0 = *(const v8s*)&Al[cur][ar][kc];
    v8s al1 = *(const v8s*)&Al[cur][ar + 16][kc];
    v8s bh0 = *(const v8s*)&Bh[cur][br][kc];
    v8s bh1 = *(const v8s*)&Bh[cur][br + 16][kc];
    v8s bl0 = *(const v8s*)&Bl[cur][br][kc];
    v8s bl1 = *(const v8s*)&Bl[cur][br + 16][kc];
    acc00 = MFMA(ah0, bh0, acc00, 0, 0, 0);
    acc00 = MFMA(ah0, bl0, acc00, 0, 0, 0);
    acc00 = MFMA(al0, bh0, acc00, 0, 0, 0);
    acc01 = MFMA(ah0, bh1, acc01, 0, 0, 0);
    acc01 = MFMA(ah0, bl1, acc01, 0, 0, 0);
    acc01 = MFMA(al0, bh1, acc01, 0, 0, 0);
    acc10 = MFMA(ah1, bh0, acc10, 0, 0, 0);
    acc10 = MFMA(ah1, bl0, acc10, 0, 0, 0);
    acc10 = MFMA(al1, bh0, acc10, 0, 0, 0);
    acc11 = MFMA(ah1, bh1, acc11, 0, 0, 0);
    acc11 = MFMA(ah1, bl1, acc11, 0, 0, 0);
    acc11 = MFMA(al1, bh1, acc11, 0, 0, 0);
    if (t + 1 < nT) store(cur ^ 1);
    __syncthreads();
  }

  // epilogue: relu, dot with Wsc cols, block-reduce, ONE atomic per block.
  // All 64 rows of this tile share one segment (64 | 128, seg = p/128).
  int cbase = n0 + wn + (l & 15);
  float w0 = (cbase      < cD0) ? Wsc[cbase]      : 0.f;
  float w1 = (cbase + 16 < cD0) ? Wsc[cbase + 16] : 0.f;
  float ps[8];
#pragma unroll
  for (int r = 0; r < 4; ++r) {
    ps[r]     = fmaxf(acc00[r], 0.f) * w0 + fmaxf(acc01[r], 0.f) * w1;
    ps[4 + r] = fmaxf(acc10[r], 0.f) * w0 + fmaxf(acc11[r], 0.f) * w1;
  }
#pragma unroll
  for (int m = 1; m < 16; m <<= 1) {
#pragma unroll
    for (int q = 0; q < 8; ++q) ps[q] += __shfl_xor(ps[q], m, 64);
  }
  if ((l & 15) == 0) {
    float local = 0.f;
#pragma unroll
    for (int q = 0; q < 8; ++q) local += ps[q];
    red[w * 4 + (l >> 4)] = local;
  }
  __syncthreads();
  if (tid == 0) {
    float t = 0.f;
#pragma unroll
    for (int i = 0; i < 16; ++i) t += red[i];
    atomicAdd(outp + cm[(size_t)m0 * 3], t * (1.f / 128.f));
  }
}

// ---------------- nei_label (Ra read from ld-600 packed buffer) -------------
__global__ __launch_bounds__(320) void nei_label2_k(
    const float* __restrict__ RaR, const float* __restrict__ RbR,
    const int* __restrict__ agR, const int* __restrict__ bgR,
    const int* __restrict__ nnbR, float* __restrict__ outR,
    const float* __restrict__ RaG, const float* __restrict__ RbG,
    const int* __restrict__ agG, const int* __restrict__ bgG,
    const int* __restrict__ nnbG, float* __restrict__ outG,
    int ldRa)
{
  int node = blockIdx.x;
  const float *Ra, *Rb; const int *ag, *bg, *nnb; float* out; int Nn, loc;
  if (node < Mres) { Ra=RaR; Rb=RbR; ag=agR; bg=bgR; nnb=nnbR; out=outR; Nn=cNR; loc=node; }
  else { Ra=RaG; Rb=RbG; ag=agG; bg=bgG; nnb=nnbG; out=outG; Nn=cNG; loc=node-Mres; }
  int h = threadIdx.x;
  int nn = nnb[loc];
  const int* agp = ag + (size_t)loc * cMAXNB * 2;
  const int* bgp = bg + (size_t)loc * cMAXNB * 2;
  if (h < cH) {
    float s = 0.f;
    for (int k = 0; k < nn; ++k) {
      int ra = agp[2 * k] * Nn + agp[2 * k + 1];
      int rb = bgp[2 * k] * Nn + bgp[2 * k + 1];
      s += fmaxf(Ra[(size_t)ra * ldRa + h] + Rb[(size_t)rb * cH + h], 0.f);
    }
    out[(size_t)loc * cH + h] = s;
  }
}

// ---------------- kernels (final WLN output; SaSe packed ld 600) ------------
__global__ __launch_bounds__(320) void kernels2_k(
    const float* __restrict__ SaSeR, const float* __restrict__ SbR,
    const int* __restrict__ agR, const int* __restrict__ bgR,
    const int* __restrict__ nnbR, const float* __restrict__ maskR,
    float* __restrict__ outR,
    const float* __restrict__ SaSeG, const float* __restrict__ SbG,
    const int* __restrict__ agG, const int* __restrict__ bgG,
    const int* __restrict__ nnbG, const float* __restrict__ maskG,
    float* __restrict__ outG)
{
  int node = blockIdx.x;
  const float *SaSe, *Sb, *mk; const int *ag, *bg, *nnb; float* out; int Nn, loc;
  if (node < Mres) { SaSe=SaSeR; Sb=SbR; ag=agR; bg=bgR; nnb=nnbR; mk=maskR; out=outR; Nn=cNR; loc=node; }
  else { SaSe=SaSeG; Sb=SbG; ag=agG; bg=bgG; nnb=nnbG; mk=maskG; out=outG; Nn=cNG; loc=node-Mres; }
  int h = threadIdx.x;
  int nn = nnb[loc];
  const int* agp = ag + (size_t)loc * cMAXNB * 2;
  const int* bgp = bg + (size_t)loc * cMAXNB * 2;
  if (h < cH) {
    float s = 0.f;
    for (int k = 0; k < nn; ++k) {
      int ra = agp[2 * k] * Nn + agp[2 * k + 1];
      int rb = bgp[2 * k] * Nn + bgp[2 * k + 1];
      s += SaSe[(size_t)ra * 600 + h] * Sb[(size_t)rb * cH + h];
    }
    out[(size_t)loc * cH + h] = s * SaSe[(size_t)loc * 600 + 300 + h] * mk[loc];
  }
}

// ---------------- attention + ctx + h assembly (round-6 verified) -----------
#define AIT 4
__global__ __launch_bounds__(256) void att_ctx_h_k(
    const float* __restrict__ U, const float* __restrict__ V,
    const float* __restrict__ att_w, const float* __restrict__ rgh,
    const float* __restrict__ kern, const float* __restrict__ qm,
    float* __restrict__ h)
{
  __shared__ float attL[AIT][cNG];
  int blk = blockIdx.x;                       // 16 * 24 = 384 blocks
  int b = blk / (cNR / AIT);
  int it = blk - b * (cNR / AIT);
  int row0 = b * cNR + it * AIT;
  int tid = threadIdx.x, lane = tid & 63, w = tid >> 6;
  int n0 = lane * 4, n1 = 256 + lane * 4;
  bool v1 = (lane < 11);                      // cols 256..299 covered by lanes 0..10
  float4 z4 = make_float4(0.f, 0.f, 0.f, 0.f);

  float4 u[AIT][2], wv[2];
  wv[0] = *(const float4*)(att_w + n0);
  wv[1] = v1 ? *(const float4*)(att_w + n1) : z4;
#pragma unroll
  for (int i = 0; i < AIT; ++i) {
    const float* Ur = U + (size_t)(row0 + i) * cH;
    u[i][0] = *(const float4*)(Ur + n0);
    u[i][1] = v1 ? *(const float4*)(Ur + n1) : z4;
  }

  for (int r = 0; r < 4; ++r) {
    int jb = w * 16 + r * 4;
    float4 vv[4][2];
#pragma unroll
    for (int q = 0; q < 4; ++q) {
      const float* Vr = V + (size_t)(b * cNG + jb + q) * cH;
      vv[q][0] = *(const float4*)(Vr + n0);
      vv[q][1] = v1 ? *(const float4*)(Vr + n1) : z4;
    }
    float s[4][AIT];
#pragma unroll
    for (int q = 0; q < 4; ++q)
#pragma unroll
      for (int i = 0; i < AIT; ++i) {
        float acc = 0.f;
#pragma unroll
        for (int pp = 0; pp < 2; ++pp) {
          float4 uu = u[i][pp], vq = vv[q][pp], ww = wv[pp];
          acc += fmaxf(uu.x + vq.x, 0.f) * ww.x;
          acc += fmaxf(uu.y + vq.y, 0.f) * ww.y;
          acc += fmaxf(uu.z + vq.z, 0.f) * ww.z;
          acc += fmaxf(uu.w + vq.w, 0.f) * ww.w;
        }
        s[q][i] = acc;
      }
#pragma unroll
    for (int m = 1; m < 64; m <<= 1)
#pragma unroll
      for (int q = 0; q < 4; ++q)
#pragma unroll
        for (int i = 0; i < AIT; ++i)
          s[q][i] += __shfl_xor(s[q][i], m);
    if (lane < 16) {
      float sv = 0.f;
#pragma unroll
      for (int q = 0; q < 4; ++q)
#pragma unroll
        for (int i = 0; i < AIT; ++i)
          if (lane == q * 4 + i) sv = s[q][i];
      attL[lane & 3][jb + (lane >> 2)] = 1.f / (1.f + expf(-sv));
    }
  }
  __syncthreads();

  // ctx: wave w owns row i=w; att coefficients broadcast from LDS
  const float* rgb = rgh + (size_t)b * cNG * cH;
  float* hrow = h + (size_t)(row0 + w) * cF;
  for (int c = lane; c < 75; c += 64) {
    float4 p = z4;
    for (int j = 0; j < cNG; ++j) {
      float aj = attL[w][j];
      float4 rv = *(const float4*)(rgb + (size_t)j * cH + c * 4);
      p.x += aj * rv.x; p.y += aj * rv.y; p.z += aj * rv.z; p.w += aj * rv.w;
    }
    *(float4*)(hrow + cH + c * 4) = p;
  }
  // copy kern / qm segments of h
  for (int idx = tid; idx < AIT * 75; idx += 256) {
    int i = idx / 75, c = idx - i * 75;
    *(float4*)(h + (size_t)(row0 + i) * cF + c * 4) =
        *(const float4*)(kern + (size_t)(row0 + i) * cH + c * 4);
  }
  for (int idx = tid; idx < AIT * 40; idx += 256) {
    int i = idx / 40, c = idx - i * 40;
    *(float4*)(h + (size_t)(row0 + i) * cF + 2 * cH + c * 4) =
        *(const float4*)(qm + (size_t)(row0 + i) * cQM + c * 4);
  }
}

// ---------------------------------------------------------------------------
extern "C" void kernel_launch(void* const* d_in, const int* in_sizes, int n_in,
                              void* d_out, int out_size, void* d_ws, size_t ws_size,
                              hipStream_t stream)
{
  (void)in_sizes; (void)n_in; (void)out_size; (void)ws_size;
  const float* res_atom = (const float*)d_in[0];
  const float* res_bond = (const float*)d_in[1];
  const int*   res_ag   = (const int*)d_in[2];
  const int*   res_bg   = (const int*)d_in[3];
  const int*   res_nnb  = (const int*)d_in[4];
  const float* res_mask = (const float*)d_in[5];
  const float* rg_atom  = (const float*)d_in[6];
  const float* rg_bond  = (const float*)d_in[7];
  const int*   rg_ag    = (const int*)d_in[8];
  const int*   rg_bg    = (const int*)d_in[9];
  const int*   rg_nnb   = (const int*)d_in[10];
  const float* rg_mask  = (const float*)d_in[11];
  const int*   core     = (const int*)d_in[12];
  const float* qm       = (const float*)d_in[13];
  const float* connect  = (const float*)d_in[14];
  const float* Wm[2][6];   // [side][atom,na,nb,self,U2,U1]
  for (int s = 0; s < 2; ++s)
    for (int k = 0; k < 6; ++k) Wm[s][k] = (const float*)d_in[15 + s * 6 + k];
  const float* W_att_h  = (const float*)d_in[27];
  const float* W_att_s  = (const float*)d_in[28];
  const float* W_score0 = (const float*)d_in[29];
  const float* W_score  = (const float*)d_in[30];
  float* out = (float*)d_out;

  float* ws = (float*)d_ws;
  size_t off = 0;
  auto alloc = [&](size_t nfloat) {
    float* p = ws + off;
    off += (nfloat + 63) & ~(size_t)63;
    return p;
  };
  auto allocU = [&](size_t nush) {
    return (unsigned short*)alloc((nush + 1) / 2);
  };

  float* afA_r  = alloc((size_t)Mres * cH);
  float* afB_r  = alloc((size_t)Mres * cH);
  float* Rb_r   = alloc((size_t)Mres * cH);
  float* Sb_r   = alloc((size_t)Mres * cH);
  float* RaU1_r = alloc((size_t)Mres * 600);
  float* nei_r  = alloc((size_t)Mres * cH);
  float* kern_r = alloc((size_t)Mres * cH);
  float* afA_g  = alloc((size_t)Mrg * cH);
  float* afB_g  = alloc((size_t)Mrg * cH);
  float* Rb_g   = alloc((size_t)Mrg * cH);
  float* Sb_g   = alloc((size_t)Mrg * cH);
  float* RaU1_g = alloc((size_t)Mrg * 600);
  float* nei_g  = alloc((size_t)Mrg * cH);
  float* kern_g = alloc((size_t)Mrg * cH);
  float* U      = alloc((size_t)Mres * cH);
  float* V      = alloc((size_t)Mrg * cH);
  float* h760   = alloc((size_t)Mres * cF);

  // weight buffers [N][Kp] hi/lo, per side
  unsigned short *atomT_h[2], *atomT_l[2], *nbT_h[2], *nbT_l[2];
  unsigned short *U2bT_h[2], *U2bT_l[2], *cat1_h[2], *cat1_l[2];
  unsigned short *cat2_h[2], *cat2_l[2], *U1bT_h[2], *U1bT_l[2];
  for (int s = 0; s < 2; ++s) {
    atomT_h[s] = allocU((size_t)300 * 128); atomT_l[s] = allocU((size_t)300 * 128);
    nbT_h[s]   = allocU((size_t)300 * 32);  nbT_l[s]   = allocU((size_t)300 * 32);
    U2bT_h[s]  = allocU((size_t)300 * 32);  U2bT_l[s]  = allocU((size_t)300 * 32);
    cat1_h[s]  = allocU((size_t)600 * 320); cat1_l[s]  = allocU((size_t)600 * 320);
    cat2_h[s]  = allocU((size_t)600 * 320); cat2_l[s]  = allocU((size_t)600 * 320);
    U1bT_h[s]  = allocU((size_t)300 * 320); U1bT_l[s]  = allocU((size_t)300 * 320);
  }
  unsigned short* attT_h = allocU((size_t)300 * 320);
  unsigned short* attT_l = allocU((size_t)300 * 320);
  unsigned short* sc0T_h = allocU((size_t)770 * 800);
  unsigned short* sc0T_l = allocU((size_t)770 * 800);

  // ---- single prep launch (18 transposes + out[16] zero)
  {
    PrepArgs pa{};
    int e = 0, base = 0;
    auto add = [&](const float* W, unsigned short* ht, unsigned short* lt,
                   int K, int N, int Kp) {
      pa.e[e] = {W, ht, lt, K, N, Kp};
      pa.bases[e] = base;
      base += N * Kp;
      ++e;
    };
    for (int s = 0; s < 2; ++s) {
      add(Wm[s][0], atomT_h[s], atomT_l[s], cAF, cH, 128);                 // atom
      add(Wm[s][2], nbT_h[s],   nbT_l[s],   cBF, cH, 32);                  // nei_bond
      add(Wm[s][4] + (size_t)cH * cH, U2bT_h[s], U2bT_l[s], cBF, cH, 32);  // U2 bot
      add(Wm[s][4], cat1_h[s],               cat1_l[s],               cH, cH, 320); // U2 top
      add(Wm[s][5], cat1_h[s] + 300 * 320,   cat1_l[s] + 300 * 320,   cH, cH, 320); // U1 top
      add(Wm[s][1], cat2_h[s],               cat2_l[s],               cH, cH, 320); // nei_atom
      add(Wm[s][3], cat2_h[s] + 300 * 320,   cat2_l[s] + 300 * 320,   cH, cH, 320); // self
      add(Wm[s][5] + (size_t)cH * cH, U1bT_h[s], U1bT_l[s], cH, cH, 320);  // U1 bot
    }
    add(W_att_h,  attT_h, attT_l, cH, cH, 320);
    add(W_score0, sc0T_h, sc0T_l, cD0, cD0, 800);
    pa.e[e] = {nullptr, (unsigned short*)out, nullptr, 0, 0, 0};
    pa.bases[e] = base; base += cB; ++e;
    pa.bases[e] = base;
    pa.nent = e;
    prep_k<<<dim3((base + 255) / 256), dim3(256), 0, stream>>>(pa);
  }

  dim3 blk(256);
  GArg zero{};
  auto gplain = [&](const float* A, const unsigned short* Wh, const unsigned short* Wl,
                    float* C, int ldC, int M, int K, int Kp, int act,
                    const float* bias = nullptr, int ldb = 0) {
    GArg g{};
    g.A = A; g.Wh = Wh; g.Wl = Wl; g.bias = bias; g.ldBias = ldb;
    g.C = C; g.ldC = ldC; g.M = M; g.K = K; g.Kp = Kp; g.act = act;
    return g;
  };

  const int MT = Mres / 32;   // 48 row tiles (rg blocks exit via m0>=M guard)

  // prologue: af0=relu(atom@W_atom); Rb=bond@U2b; Sb=relu(bond@W_nb)
  {
    GArgs6 ga{{
      gplain(res_atom, atomT_h[0], atomT_l[0], afA_r, cH, Mres, cAF, 128, 1),
      gplain(rg_atom,  atomT_h[1], atomT_l[1], afA_g, cH, Mrg,  cAF, 128, 1),
      gplain(res_bond, U2bT_h[0],  U2bT_l[0],  Rb_r,  cH, Mres, cBF, 32, 0),
      gplain(rg_bond,  U2bT_h[1],  U2bT_l[1],  Rb_g,  cH, Mrg,  cBF, 32, 0),
      gplain(res_bond, nbT_h[0],   nbT_l[0],   Sb_r,  cH, Mres, cBF, 32, 1),
      gplain(rg_bond,  nbT_h[1],   nbT_l[1],   Sb_g,  cH, Mrg,  cBF, 32, 1),
    }};
    gemm32<<<dim3(5, MT, 6), blk, 0, stream>>>(ga, cH);
  }

  float* af_r = afA_r; float* afo_r = afB_r;
  float* af_g = afA_g; float* afo_g = afB_g;
  for (int it = 0; it < cDEPTH - 1; ++it) {
    // L1: [Ra | preU1] = af @ [U2t | U1t]  (N=600, no act)
    {
      GArgs6 ga{{
        gplain(af_r, cat1_h[0], cat1_l[0], RaU1_r, 600, Mres, cH, 320, 0),
        gplain(af_g, cat1_h[1], cat1_l[1], RaU1_g, 600, Mrg,  cH, 320, 0),
        zero, zero, zero, zero,
      }};
      gemm32<<<dim3(10, MT, 2), blk, 0, stream>>>(ga, 600);
    }
    // nei = gather-sum relu(Ra[ga] + Rb[gb])   (Ra ld 600)
    nei_label2_k<<<dim3(Mres + Mrg), dim3(320), 0, stream>>>(
        RaU1_r, Rb_r, res_ag, res_bg, res_nnb, nei_r,
        RaU1_g, Rb_g, rg_ag, rg_bg, rg_nnb, nei_g, 600);
    // L2: af' = relu( nei @ U1b + preU1 )
    {
      GArgs6 ga{{
        gplain(nei_r, U1bT_h[0], U1bT_l[0], afo_r, cH, Mres, cH, 320, 1,
               RaU1_r + 300, 600),
        gplain(nei_g, U1bT_h[1], U1bT_l[1], afo_g, cH, Mrg, cH, 320, 1,
               RaU1_g + 300, 600),
        zero, zero, zero, zero,
      }};
      gemm32<<<dim3(5, MT, 2), blk, 0, stream>>>(ga, cH);
    }
    { float* tmp = af_r; af_r = afo_r; afo_r = tmp; }
    { float* tmp = af_g; af_g = afo_g; afo_g = tmp; }
  }

  // final iter: [Sa | Self] = relu(af @ [na | self])  (N=600)
  {
    GArgs6 ga{{
      gplain(af_r, cat2_h[0], cat2_l[0], RaU1_r, 600, Mres, cH, 320, 1),
      gplain(af_g, cat2_h[1], cat2_l[1], RaU1_g, 600, Mrg,  cH, 320, 1),
      zero, zero, zero, zero,
    }};
    gemm32<<<dim3(10, MT, 2), blk, 0, stream>>>(ga, 600);
  }
  kernels2_k<<<dim3(Mres + Mrg), dim3(320), 0, stream>>>(
      RaU1_r, Sb_r, res_ag, res_bg, res_nnb, res_mask, kern_r,
      RaU1_g, Sb_g, rg_ag, rg_bg, rg_nnb, rg_mask, kern_g);

  // U / V = kern @ W_att_h
  {
    GArgs6 ga{{
      gplain(kern_r, attT_h, attT_l, U, cH, Mres, cH, 320, 0),
      gplain(kern_g, attT_h, attT_l, V, cH, Mrg,  cH, 320, 0),
      zero, zero, zero, zero,
    }};
    gemm32<<<dim3(5, MT, 2), blk, 0, stream>>>(ga, cH);
  }
  att_ctx_h_k<<<dim3(cB * (cNR / AIT)), dim3(256), 0, stream>>>(
      U, V, W_att_s, kern_g, kern_r, qm, h760);

  score_mfma_k<<<dim3(13, cP / 64), blk, 0, stream>>>(
      h760, connect, core, sc0T_h, sc0T_l, W_score, out);
}

// Round 13
// 241.108 us; speedup vs baseline: 4.3090x; 1.0034x over previous
//
#include <hip/hip_runtime.h>

// ---------------------------------------------------------------------------
// QMWLNPairwiseAtomClassifier — round 12 (= round 9 + score->out fusion):
//  * verified round-9 dispatch structure (coop fusion reverted: grid.sync on
//    8-XCD flushes L2 per sync -> 170MB refetch, 1.2ms; measured round 11)
//  * score_mfma epilogue: block-reduce + 1 atomicAdd directly into d_out
//    (seg_final + pairsum deleted; prep zeroes out[16])
// ---------------------------------------------------------------------------

constexpr int cB = 16, cNR = 96, cNG = 64;
constexpr int cAF = 98, cBF = 6;
constexpr int cH = 300, cQM = 160, cMAXNB = 10, cDEPTH = 4;
constexpr int cP = 2048;
constexpr int cF = 2 * cH + cQM;   // 760
constexpr int cD0 = cF + 10;       // 770

constexpr int Mres = cB * cNR;     // 1536
constexpr int Mrg  = cB * cNG;     // 1024

typedef __attribute__((ext_vector_type(8))) short v8s;
typedef __attribute__((ext_vector_type(4))) float v4f;

__device__ inline unsigned short f2bf(float f) {
  unsigned u = __float_as_uint(f);
  u += 0x7FFF + ((u >> 16) & 1);          // RNE
  return (unsigned short)(u >> 16);
}
__device__ inline float bf2f(unsigned short s) {
  return __uint_as_float(((unsigned)s) << 16);
}

// ---------------- prep: transpose+split all weights, zero out[16] -----------
struct PrepEnt { const float* W; unsigned short* hiT; unsigned short* loT;
                 int K, N, Kpad; };
struct PrepArgs { PrepEnt e[19]; int bases[20]; int nent; };

__global__ __launch_bounds__(256) void prep_k(PrepArgs pa)
{
  int g = blockIdx.x * 256 + threadIdx.x;
  if (g >= pa.bases[pa.nent]) return;
  int idx = 0;
  while (g >= pa.bases[idx + 1]) ++idx;
  PrepEnt p = pa.e[idx];
  int local = g - pa.bases[idx];
  if (!p.W) { ((float*)p.hiT)[local] = 0.f; return; }
  int n = local / p.Kpad, k = local - n * p.Kpad;
  float w = (k < p.K) ? p.W[(size_t)k * p.N + n] : 0.f;
  unsigned short h = f2bf(w);
  p.hiT[local] = h;
  p.loT[local] = f2bf(w - bf2f(h));
}

// ---------------- MFMA GEMM (BM=32): C = act(A@W + bias) --------------------
struct GArg {
  const float* A;                                      // M x K, ld=K
  const unsigned short* Wh; const unsigned short* Wl;  // [N][Kp]
  const float* bias; int ldBias;
  float* C; int ldC;
  int M, K, Kp, act;
};
struct GArgs6 { GArg a[6]; };

#define MFMA __builtin_amdgcn_mfma_f32_16x16x32_bf16

__global__ __launch_bounds__(256) void gemm32(GArgs6 ga, int N)
{
  GArg g = ga.a[blockIdx.z];
  int m0 = blockIdx.y * 32;
  if (m0 >= g.M) return;
  int n0 = blockIdx.x * 64;
  int nT = g.Kp >> 5;

  __shared__ unsigned short Ah[2][32][40];
  __shared__ unsigned short Al[2][32][40];
  __shared__ unsigned short Bh[2][64][40];
  __shared__ unsigned short Bl[2][64][40];

  int tid = threadIdx.x;
  bool doA = tid < 128;
  int smA = tid >> 2;           // 0..31 (valid when doA)
  int skA = (tid & 3) << 3;
  int smB = tid >> 2;           // 0..63
  int skB = (tid & 3) << 3;
  int gmA = m0 + smA;

  float areg[8];
  uint4 bh_reg, bl_reg;

  auto fetch = [&](int kv0) {
    if (doA) {
      int kk = kv0 + skA;
      const float* src = g.A + (size_t)gmA * g.K;
      if (((g.K & 3) == 0) && kk + 7 < g.K) {
        float4 v0 = *(const float4*)(src + kk);
        float4 v1 = *(const float4*)(src + kk + 4);
        areg[0]=v0.x; areg[1]=v0.y; areg[2]=v0.z; areg[3]=v0.w;
        areg[4]=v1.x; areg[5]=v1.y; areg[6]=v1.z; areg[7]=v1.w;
      } else {
#pragma unroll
        for (int j = 0; j < 8; ++j) areg[j] = (kk + j < g.K) ? src[kk + j] : 0.f;
      }
    }
    int gn = n0 + smB;
    int kkb = kv0 + skB;
    if (gn < N) {
      size_t o = (size_t)gn * g.Kp + kkb;
      bh_reg = *(const uint4*)(g.Wh + o);
      bl_reg = *(const uint4*)(g.Wl + o);
    } else {
      bh_reg = make_uint4(0,0,0,0); bl_reg = make_uint4(0,0,0,0);
    }
  };

  auto store = [&](int buf) {
    if (doA) {
      unsigned hs[8], ls[8];
#pragma unroll
      for (int j = 0; j < 8; ++j) {
        unsigned short hv = f2bf(areg[j]);
        hs[j] = hv;
        ls[j] = f2bf(areg[j] - bf2f(hv));
      }
      uint4 hh, ll;
      hh.x = hs[0] | (hs[1] << 16); hh.y = hs[2] | (hs[3] << 16);
      hh.z = hs[4] | (hs[5] << 16); hh.w = hs[6] | (hs[7] << 16);
      ll.x = ls[0] | (ls[1] << 16); ll.y = ls[2] | (ls[3] << 16);
      ll.z = ls[4] | (ls[5] << 16); ll.w = ls[6] | (ls[7] << 16);
      *(uint4*)&Ah[buf][smA][skA] = hh;
      *(uint4*)&Al[buf][smA][skA] = ll;
    }
    *(uint4*)&Bh[buf][smB][skB] = bh_reg;
    *(uint4*)&Bl[buf][smB][skB] = bl_reg;
  };

  int l = tid & 63, w = tid >> 6;
  int wr = (w >> 1) << 4;       // 0 / 16
  int wc = (w & 1) << 5;        // 0 / 32
  int arow = wr + (l & 15);
  int brow = wc + (l & 15);
  int kc = (l >> 4) << 3;

  v4f acc0 = {0,0,0,0}, acc1 = {0,0,0,0};

  fetch(0); store(0); __syncthreads();
  for (int t = 0; t < nT; ++t) {
    if (t + 1 < nT) fetch((t + 1) << 5);
    int cur = t & 1;
    v8s ah  = *(const v8s*)&Ah[cur][arow][kc];
    v8s al  = *(const v8s*)&Al[cur][arow][kc];
    v8s bh0 = *(const v8s*)&Bh[cur][brow][kc];
    v8s bh1 = *(const v8s*)&Bh[cur][brow + 16][kc];
    v8s bl0 = *(const v8s*)&Bl[cur][brow][kc];
    v8s bl1 = *(const v8s*)&Bl[cur][brow + 16][kc];
    acc0 = MFMA(ah, bh0, acc0, 0, 0, 0);
    acc0 = MFMA(ah, bl0, acc0, 0, 0, 0);
    acc0 = MFMA(al, bh0, acc0, 0, 0, 0);
    acc1 = MFMA(ah, bh1, acc1, 0, 0, 0);
    acc1 = MFMA(ah, bl1, acc1, 0, 0, 0);
    acc1 = MFMA(al, bh1, acc1, 0, 0, 0);
    if (t + 1 < nT) store(cur ^ 1);
    __syncthreads();
  }

  int rbase = m0 + wr + ((l >> 4) << 2);
  int cbase = n0 + wc + (l & 15);
  v4f accs[2] = {acc0, acc1};
#pragma unroll
  for (int fj = 0; fj < 2; ++fj) {
    int gn = cbase + fj * 16;
    if (gn >= N) continue;
    float* Cp = g.C + (size_t)rbase * g.ldC + gn;
    const float* Bp = g.bias ? g.bias + (size_t)rbase * g.ldBias + gn : nullptr;
#pragma unroll
    for (int r = 0; r < 4; ++r) {
      float v = accs[fj][r];
      if (Bp) v += Bp[(size_t)r * g.ldBias];
      if (g.act) v = fmaxf(v, 0.f);
      Cp[(size_t)r * g.ldC] = v;
    }
  }
}

// ---------------- score GEMM + fused rh·Wsc -> one atomicAdd into out -------
__global__ __launch_bounds__(256) void score_mfma_k(
    const float* __restrict__ h, const float* __restrict__ conn,
    const int* __restrict__ cm,
    const unsigned short* __restrict__ W0h, const unsigned short* __restrict__ W0l,
    const float* __restrict__ Wsc, float* __restrict__ outp)
{
  const int Kp = 800;
  const int nT = Kp >> 5;           // 25
  int m0 = blockIdx.y * 64;
  int n0 = blockIdx.x * 64;

  __shared__ unsigned short Ah[2][64][40];
  __shared__ unsigned short Al[2][64][40];
  __shared__ unsigned short Bh[2][64][40];
  __shared__ unsigned short Bl[2][64][40];
  __shared__ float red[16];

  int tid = threadIdx.x;
  int sm = tid >> 2;
  int sk = (tid & 3) << 3;

  int p = m0 + sm;
  int s3 = cm[p * 3 + 0];
  const float* h1 = h + (size_t)(s3 * cNR + cm[p * 3 + 1]) * cF;
  const float* h2 = h + (size_t)(s3 * cNR + cm[p * 3 + 2]) * cF;
  const float* cp = conn + (size_t)p * 10;

  float areg[8];
  uint4 bh_reg, bl_reg;

  auto fetch = [&](int kv0) {
    int kv = kv0 + sk;
    if (kv + 7 < cF) {
      float4 u = *(const float4*)(h1 + kv);
      float4 v = *(const float4*)(h2 + kv);
      float4 u2 = *(const float4*)(h1 + kv + 4);
      float4 v2 = *(const float4*)(h2 + kv + 4);
      areg[0]=u.x+v.x; areg[1]=u.y+v.y; areg[2]=u.z+v.z; areg[3]=u.w+v.w;
      areg[4]=u2.x+v2.x; areg[5]=u2.y+v2.y; areg[6]=u2.z+v2.z; areg[7]=u2.w+v2.w;
    } else {
#pragma unroll
      for (int j = 0; j < 8; ++j) {
        int k = kv + j;
        float v = 0.f;
        if (k < cF) v = h1[k] + h2[k];
        else if (k < cD0) v = cp[k - cF];
        areg[j] = v;
      }
    }
    int gn = n0 + sm;
    if (gn < cD0) {
      size_t o = (size_t)gn * Kp + kv;
      bh_reg = *(const uint4*)(W0h + o);
      bl_reg = *(const uint4*)(W0l + o);
    } else {
      bh_reg = make_uint4(0,0,0,0); bl_reg = make_uint4(0,0,0,0);
    }
  };

  auto store = [&](int buf) {
    unsigned hs[8], ls[8];
#pragma unroll
    for (int j = 0; j < 8; ++j) {
      unsigned short hv = f2bf(areg[j]);
      hs[j] = hv;
      ls[j] = f2bf(areg[j] - bf2f(hv));
    }
    uint4 hh, ll;
    hh.x = hs[0] | (hs[1] << 16); hh.y = hs[2] | (hs[3] << 16);
    hh.z = hs[4] | (hs[5] << 16); hh.w = hs[6] | (hs[7] << 16);
    ll.x = ls[0] | (ls[1] << 16); ll.y = ls[2] | (ls[3] << 16);
    ll.z = ls[4] | (ls[5] << 16); ll.w = ls[6] | (ls[7] << 16);
    *(uint4*)&Ah[buf][sm][sk] = hh;
    *(uint4*)&Al[buf][sm][sk] = ll;
    *(uint4*)&Bh[buf][sm][sk] = bh_reg;
    *(uint4*)&Bl[buf][sm][sk] = bl_reg;
  };

  int l = tid & 63, w = tid >> 6;
  int wm = (w >> 1) << 5, wn = (w & 1) << 5;
  int ar = wm + (l & 15), br = wn + (l & 15);
  int kc = (l >> 4) << 3;

  v4f acc00 = {0,0,0,0}, acc01 = {0,0,0,0}, acc10 = {0,0,0,0}, acc11 = {0,0,0,0};

  fetch(0); store(0); __syncthreads();
  for (int t = 0; t < nT; ++t) {
    if (t + 1 < nT) fetch((t + 1) << 5);
    int cur = t & 1;
    v8s ah0 = *(const v8s*)&Ah[cur][ar][kc];
    v8s ah1 = *(const v8s*)&Ah[cur][ar + 16][kc];
    v8s al0 = *(const v8s*)&Al[cur][ar][kc];
    v8s al1 = *(const v8s*)&Al[cur][ar + 16][kc];
    v8s bh0 = *(const v8s*)&Bh[cur][br][kc];
    v8s bh1 = *(const v8s*)&Bh[cur][br + 16][kc];
    v8s bl0 = *(const v8s*)&Bl[cur][br][kc];
    v8s bl1 = *(const v8s*)&Bl[cur][br + 16][kc];
    acc00 = MFMA(ah0, bh0, acc00, 0, 0, 0);
    acc00 = MFMA(ah0, bl0, acc00, 0, 0, 0);
    acc00 = MFMA(al0, bh0, acc00, 0, 0, 0);
    acc01 = MFMA(ah0, bh1, acc01, 0, 0, 0);
    acc01 = MFMA(ah0, bl1, acc01, 0, 0, 0);
    acc01 = MFMA(al0, bh1, acc01, 0, 0, 0);
    acc10 = MFMA(ah1, bh0, acc10, 0, 0, 0);
    acc10 = MFMA(ah1, bl0, acc10, 0, 0, 0);
    acc10 = MFMA(al1, bh0, acc10, 0, 0, 0);
    acc11 = MFMA(ah1, bh1, acc11, 0, 0, 0);
    acc11 = MFMA(ah1, bl1, acc11, 0, 0, 0);
    acc11 = MFMA(al1, bh1, acc11, 0, 0, 0);
    if (t + 1 < nT) store(cur ^ 1);
    __syncthreads();
  }

  // epilogue: relu, dot with Wsc cols, block-reduce, ONE atomic per block.
  // All 64 rows of this tile share one segment (64 | 128, seg = p/128).
  int cbase = n0 + wn + (l & 15);
  float w0 = (cbase      < cD0) ? Wsc[cbase]      : 0.f;
  float w1 = (cbase + 16 < cD0) ? Wsc[cbase + 16] : 0.f;
  float ps[8];
#pragma unroll
  for (int r = 0; r < 4; ++r) {
    ps[r]     = fmaxf(acc00[r], 0.f) * w0 + fmaxf(acc01[r], 0.f) * w1;
    ps[4 + r] = fmaxf(acc10[r], 0.f) * w0 + fmaxf(acc11[r], 0.f) * w1;
  }
#pragma unroll
  for (int m = 1; m < 16; m <<= 1) {
#pragma unroll
    for (int q = 0; q < 8; ++q) ps[q] += __shfl_xor(ps[q], m, 64);
  }
  if ((l & 15) == 0) {
    float local = 0.f;
#pragma unroll
    for (int q = 0; q < 8; ++q) local += ps[q];
    red[w * 4 + (l >> 4)] = local;
  }
  __syncthreads();
  if (tid == 0) {
    float t = 0.f;
#pragma unroll
    for (int i = 0; i < 16; ++i) t += red[i];
    atomicAdd(outp + cm[(size_t)m0 * 3], t * (1.f / 128.f));
  }
}

// ---------------- nei_label (Ra read from ld-600 packed buffer) -------------
__global__ __launch_bounds__(320) void nei_label2_k(
    const float* __restrict__ RaR, const float* __restrict__ RbR,
    const int* __restrict__ agR, const int* __restrict__ bgR,
    const int* __restrict__ nnbR, float* __restrict__ outR,
    const float* __restrict__ RaG, const float* __restrict__ RbG,
    const int* __restrict__ agG, const int* __restrict__ bgG,
    const int* __restrict__ nnbG, float* __restrict__ outG,
    int ldRa)
{
  int node = blockIdx.x;
  const float *Ra, *Rb; const int *ag, *bg, *nnb; float* out; int Nn, loc;
  if (node < Mres) { Ra=RaR; Rb=RbR; ag=agR; bg=bgR; nnb=nnbR; out=outR; Nn=cNR; loc=node; }
  else { Ra=RaG; Rb=RbG; ag=agG; bg=bgG; nnb=nnbG; out=outG; Nn=cNG; loc=node-Mres; }
  int h = threadIdx.x;
  int nn = nnb[loc];
  const int* agp = ag + (size_t)loc * cMAXNB * 2;
  const int* bgp = bg + (size_t)loc * cMAXNB * 2;
  if (h < cH) {
    float s = 0.f;
    for (int k = 0; k < nn; ++k) {
      int ra = agp[2 * k] * Nn + agp[2 * k + 1];
      int rb = bgp[2 * k] * Nn + bgp[2 * k + 1];
      s += fmaxf(Ra[(size_t)ra * ldRa + h] + Rb[(size_t)rb * cH + h], 0.f);
    }
    out[(size_t)loc * cH + h] = s;
  }
}

// ---------------- kernels (final WLN output; SaSe packed ld 600) ------------
__global__ __launch_bounds__(320) void kernels2_k(
    const float* __restrict__ SaSeR, const float* __restrict__ SbR,
    const int* __restrict__ agR, const int* __restrict__ bgR,
    const int* __restrict__ nnbR, const float* __restrict__ maskR,
    float* __restrict__ outR,
    const float* __restrict__ SaSeG, const float* __restrict__ SbG,
    const int* __restrict__ agG, const int* __restrict__ bgG,
    const int* __restrict__ nnbG, const float* __restrict__ maskG,
    float* __restrict__ outG)
{
  int node = blockIdx.x;
  const float *SaSe, *Sb, *mk; const int *ag, *bg, *nnb; float* out; int Nn, loc;
  if (node < Mres) { SaSe=SaSeR; Sb=SbR; ag=agR; bg=bgR; nnb=nnbR; mk=maskR; out=outR; Nn=cNR; loc=node; }
  else { SaSe=SaSeG; Sb=SbG; ag=agG; bg=bgG; nnb=nnbG; mk=maskG; out=outG; Nn=cNG; loc=node-Mres; }
  int h = threadIdx.x;
  int nn = nnb[loc];
  const int* agp = ag + (size_t)loc * cMAXNB * 2;
  const int* bgp = bg + (size_t)loc * cMAXNB * 2;
  if (h < cH) {
    float s = 0.f;
    for (int k = 0; k < nn; ++k) {
      int ra = agp[2 * k] * Nn + agp[2 * k + 1];
      int rb = bgp[2 * k] * Nn + bgp[2 * k + 1];
      s += SaSe[(size_t)ra * 600 + h] * Sb[(size_t)rb * cH + h];
    }
    out[(size_t)loc * cH + h] = s * SaSe[(size_t)loc * 600 + 300 + h] * mk[loc];
  }
}

// ---------------- attention + ctx + h assembly (round-6 verified) -----------
#define AIT 4
__global__ __launch_bounds__(256) void att_ctx_h_k(
    const float* __restrict__ U, const float* __restrict__ V,
    const float* __restrict__ att_w, const float* __restrict__ rgh,
    const float* __restrict__ kern, const float* __restrict__ qm,
    float* __restrict__ h)
{
  __shared__ float attL[AIT][cNG];
  int blk = blockIdx.x;                       // 16 * 24 = 384 blocks
  int b = blk / (cNR / AIT);
  int it = blk - b * (cNR / AIT);
  int row0 = b * cNR + it * AIT;
  int tid = threadIdx.x, lane = tid & 63, w = tid >> 6;
  int n0 = lane * 4, n1 = 256 + lane * 4;
  bool v1 = (lane < 11);                      // cols 256..299 covered by lanes 0..10
  float4 z4 = make_float4(0.f, 0.f, 0.f, 0.f);

  float4 u[AIT][2], wv[2];
  wv[0] = *(const float4*)(att_w + n0);
  wv[1] = v1 ? *(const float4*)(att_w + n1) : z4;
#pragma unroll
  for (int i = 0; i < AIT; ++i) {
    const float* Ur = U + (size_t)(row0 + i) * cH;
    u[i][0] = *(const float4*)(Ur + n0);
    u[i][1] = v1 ? *(const float4*)(Ur + n1) : z4;
  }

  for (int r = 0; r < 4; ++r) {
    int jb = w * 16 + r * 4;
    float4 vv[4][2];
#pragma unroll
    for (int q = 0; q < 4; ++q) {
      const float* Vr = V + (size_t)(b * cNG + jb + q) * cH;
      vv[q][0] = *(const float4*)(Vr + n0);
      vv[q][1] = v1 ? *(const float4*)(Vr + n1) : z4;
    }
    float s[4][AIT];
#pragma unroll
    for (int q = 0; q < 4; ++q)
#pragma unroll
      for (int i = 0; i < AIT; ++i) {
        float acc = 0.f;
#pragma unroll
        for (int pp = 0; pp < 2; ++pp) {
          float4 uu = u[i][pp], vq = vv[q][pp], ww = wv[pp];
          acc += fmaxf(uu.x + vq.x, 0.f) * ww.x;
          acc += fmaxf(uu.y + vq.y, 0.f) * ww.y;
          acc += fmaxf(uu.z + vq.z, 0.f) * ww.z;
          acc += fmaxf(uu.w + vq.w, 0.f) * ww.w;
        }
        s[q][i] = acc;
      }
#pragma unroll
    for (int m = 1; m < 64; m <<= 1)
#pragma unroll
      for (int q = 0; q < 4; ++q)
#pragma unroll
        for (int i = 0; i < AIT; ++i)
          s[q][i] += __shfl_xor(s[q][i], m);
    if (lane < 16) {
      float sv = 0.f;
#pragma unroll
      for (int q = 0; q < 4; ++q)
#pragma unroll
        for (int i = 0; i < AIT; ++i)
          if (lane == q * 4 + i) sv = s[q][i];
      attL[lane & 3][jb + (lane >> 2)] = 1.f / (1.f + expf(-sv));
    }
  }
  __syncthreads();

  // ctx: wave w owns row i=w; att coefficients broadcast from LDS
  const float* rgb = rgh + (size_t)b * cNG * cH;
  float* hrow = h + (size_t)(row0 + w) * cF;
  for (int c = lane; c < 75; c += 64) {
    float4 p = z4;
    for (int j = 0; j < cNG; ++j) {
      float aj = attL[w][j];
      float4 rv = *(const float4*)(rgb + (size_t)j * cH + c * 4);
      p.x += aj * rv.x; p.y += aj * rv.y; p.z += aj * rv.z; p.w += aj * rv.w;
    }
    *(float4*)(hrow + cH + c * 4) = p;
  }
  // copy kern / qm segments of h
  for (int idx = tid; idx < AIT * 75; idx += 256) {
    int i = idx / 75, c = idx - i * 75;
    *(float4*)(h + (size_t)(row0 + i) * cF + c * 4) =
        *(const float4*)(kern + (size_t)(row0 + i) * cH + c * 4);
  }
  for (int idx = tid; idx < AIT * 40; idx += 256) {
    int i = idx / 40, c = idx - i * 40;
    *(float4*)(h + (size_t)(row0 + i) * cF + 2 * cH + c * 4) =
        *(const float4*)(qm + (size_t)(row0 + i) * cQM + c * 4);
  }
}

// ---------------------------------------------------------------------------
extern "C" void kernel_launch(void* const* d_in, const int* in_sizes, int n_in,
                              void* d_out, int out_size, void* d_ws, size_t ws_size,
                              hipStream_t stream)
{
  (void)in_sizes; (void)n_in; (void)out_size; (void)ws_size;
  const float* res_atom = (const float*)d_in[0];
  const float* res_bond = (const float*)d_in[1];
  const int*   res_ag   = (const int*)d_in[2];
  const int*   res_bg   = (const int*)d_in[3];
  const int*   res_nnb  = (const int*)d_in[4];
  const float* res_mask = (const float*)d_in[5];
  const float* rg_atom  = (const float*)d_in[6];
  const float* rg_bond  = (const float*)d_in[7];
  const int*   rg_ag    = (const int*)d_in[8];
  const int*   rg_bg    = (const int*)d_in[9];
  const int*   rg_nnb   = (const int*)d_in[10];
  const float* rg_mask  = (const float*)d_in[11];
  const int*   core     = (const int*)d_in[12];
  const float* qm       = (const float*)d_in[13];
  const float* connect  = (const float*)d_in[14];
  const float* Wm[2][6];   // [side][atom,na,nb,self,U2,U1]
  for (int s = 0; s < 2; ++s)
    for (int k = 0; k < 6; ++k) Wm[s][k] = (const float*)d_in[15 + s * 6 + k];
  const float* W_att_h  = (const float*)d_in[27];
  const float* W_att_s  = (const float*)d_in[28];
  const float* W_score0 = (const float*)d_in[29];
  const float* W_score  = (const float*)d_in[30];
  float* out = (float*)d_out;

  float* ws = (float*)d_ws;
  size_t off = 0;
  auto alloc = [&](size_t nfloat) {
    float* p = ws + off;
    off += (nfloat + 63) & ~(size_t)63;
    return p;
  };
  auto allocU = [&](size_t nush) {
    return (unsigned short*)alloc((nush + 1) / 2);
  };

  float* afA_r  = alloc((size_t)Mres * cH);
  float* afB_r  = alloc((size_t)Mres * cH);
  float* Rb_r   = alloc((size_t)Mres * cH);
  float* Sb_r   = alloc((size_t)Mres * cH);
  float* RaU1_r = alloc((size_t)Mres * 600);
  float* nei_r  = alloc((size_t)Mres * cH);
  float* kern_r = alloc((size_t)Mres * cH);
  float* afA_g  = alloc((size_t)Mrg * cH);
  float* afB_g  = alloc((size_t)Mrg * cH);
  float* Rb_g   = alloc((size_t)Mrg * cH);
  float* Sb_g   = alloc((size_t)Mrg * cH);
  float* RaU1_g = alloc((size_t)Mrg * 600);
  float* nei_g  = alloc((size_t)Mrg * cH);
  float* kern_g = alloc((size_t)Mrg * cH);
  float* U      = alloc((size_t)Mres * cH);
  float* V      = alloc((size_t)Mrg * cH);
  float* h760   = alloc((size_t)Mres * cF);

  // weight buffers [N][Kp] hi/lo, per side
  unsigned short *atomT_h[2], *atomT_l[2], *nbT_h[2], *nbT_l[2];
  unsigned short *U2bT_h[2], *U2bT_l[2], *cat1_h[2], *cat1_l[2];
  unsigned short *cat2_h[2], *cat2_l[2], *U1bT_h[2], *U1bT_l[2];
  for (int s = 0; s < 2; ++s) {
    atomT_h[s] = allocU((size_t)300 * 128); atomT_l[s] = allocU((size_t)300 * 128);
    nbT_h[s]   = allocU((size_t)300 * 32);  nbT_l[s]   = allocU((size_t)300 * 32);
    U2bT_h[s]  = allocU((size_t)300 * 32);  U2bT_l[s]  = allocU((size_t)300 * 32);
    cat1_h[s]  = allocU((size_t)600 * 320); cat1_l[s]  = allocU((size_t)600 * 320);
    cat2_h[s]  = allocU((size_t)600 * 320); cat2_l[s]  = allocU((size_t)600 * 320);
    U1bT_h[s]  = allocU((size_t)300 * 320); U1bT_l[s]  = allocU((size_t)300 * 320);
  }
  unsigned short* attT_h = allocU((size_t)300 * 320);
  unsigned short* attT_l = allocU((size_t)300 * 320);
  unsigned short* sc0T_h = allocU((size_t)770 * 800);
  unsigned short* sc0T_l = allocU((size_t)770 * 800);

  // ---- single prep launch (18 transposes + out[16] zero)
  {
    PrepArgs pa{};
    int e = 0, base = 0;
    auto add = [&](const float* W, unsigned short* ht, unsigned short* lt,
                   int K, int N, int Kp) {
      pa.e[e] = {W, ht, lt, K, N, Kp};
      pa.bases[e] = base;
      base += N * Kp;
      ++e;
    };
    for (int s = 0; s < 2; ++s) {
      add(Wm[s][0], atomT_h[s], atomT_l[s], cAF, cH, 128);                 // atom
      add(Wm[s][2], nbT_h[s],   nbT_l[s],   cBF, cH, 32);                  // nei_bond
      add(Wm[s][4] + (size_t)cH * cH, U2bT_h[s], U2bT_l[s], cBF, cH, 32);  // U2 bot
      add(Wm[s][4], cat1_h[s],               cat1_l[s],               cH, cH, 320); // U2 top
      add(Wm[s][5], cat1_h[s] + 300 * 320,   cat1_l[s] + 300 * 320,   cH, cH, 320); // U1 top
      add(Wm[s][1], cat2_h[s],               cat2_l[s],               cH, cH, 320); // nei_atom
      add(Wm[s][3], cat2_h[s] + 300 * 320,   cat2_l[s] + 300 * 320,   cH, cH, 320); // self
      add(Wm[s][5] + (size_t)cH * cH, U1bT_h[s], U1bT_l[s], cH, cH, 320);  // U1 bot
    }
    add(W_att_h,  attT_h, attT_l, cH, cH, 320);
    add(W_score0, sc0T_h, sc0T_l, cD0, cD0, 800);
    pa.e[e] = {nullptr, (unsigned short*)out, nullptr, 0, 0, 0};
    pa.bases[e] = base; base += cB; ++e;
    pa.bases[e] = base;
    pa.nent = e;
    prep_k<<<dim3((base + 255) / 256), dim3(256), 0, stream>>>(pa);
  }

  dim3 blk(256);
  GArg zero{};
  auto gplain = [&](const float* A, const unsigned short* Wh, const unsigned short* Wl,
                    float* C, int ldC, int M, int K, int Kp, int act,
                    const float* bias = nullptr, int ldb = 0) {
    GArg g{};
    g.A = A; g.Wh = Wh; g.Wl = Wl; g.bias = bias; g.ldBias = ldb;
    g.C = C; g.ldC = ldC; g.M = M; g.K = K; g.Kp = Kp; g.act = act;
    return g;
  };

  const int MT = Mres / 32;   // 48 row tiles (rg blocks exit via m0>=M guard)

  // prologue: af0=relu(atom@W_atom); Rb=bond@U2b; Sb=relu(bond@W_nb)
  {
    GArgs6 ga{{
      gplain(res_atom, atomT_h[0], atomT_l[0], afA_r, cH, Mres, cAF, 128, 1),
      gplain(rg_atom,  atomT_h[1], atomT_l[1], afA_g, cH, Mrg,  cAF, 128, 1),
      gplain(res_bond, U2bT_h[0],  U2bT_l[0],  Rb_r,  cH, Mres, cBF, 32, 0),
      gplain(rg_bond,  U2bT_h[1],  U2bT_l[1],  Rb_g,  cH, Mrg,  cBF, 32, 0),
      gplain(res_bond, nbT_h[0],   nbT_l[0],   Sb_r,  cH, Mres, cBF, 32, 1),
      gplain(rg_bond,  nbT_h[1],   nbT_l[1],   Sb_g,  cH, Mrg,  cBF, 32, 1),
    }};
    gemm32<<<dim3(5, MT, 6), blk, 0, stream>>>(ga, cH);
  }

  float* af_r = afA_r; float* afo_r = afB_r;
  float* af_g = afA_g; float* afo_g = afB_g;
  for (int it = 0; it < cDEPTH - 1; ++it) {
    // L1: [Ra | preU1] = af @ [U2t | U1t]  (N=600, no act)
    {
      GArgs6 ga{{
        gplain(af_r, cat1_h[0], cat1_l[0], RaU1_r, 600, Mres, cH, 320, 0),
        gplain(af_g, cat1_h[1], cat1_l[1], RaU1_g, 600, Mrg,  cH, 320, 0),
        zero, zero, zero, zero,
      }};
      gemm32<<<dim3(10, MT, 2), blk, 0, stream>>>(ga, 600);
    }
    // nei = gather-sum relu(Ra[ga] + Rb[gb])   (Ra ld 600)
    nei_label2_k<<<dim3(Mres + Mrg), dim3(320), 0, stream>>>(
        RaU1_r, Rb_r, res_ag, res_bg, res_nnb, nei_r,
        RaU1_g, Rb_g, rg_ag, rg_bg, rg_nnb, nei_g, 600);
    // L2: af' = relu( nei @ U1b + preU1 )
    {
      GArgs6 ga{{
        gplain(nei_r, U1bT_h[0], U1bT_l[0], afo_r, cH, Mres, cH, 320, 1,
               RaU1_r + 300, 600),
        gplain(nei_g, U1bT_h[1], U1bT_l[1], afo_g, cH, Mrg, cH, 320, 1,
               RaU1_g + 300, 600),
        zero, zero, zero, zero,
      }};
      gemm32<<<dim3(5, MT, 2), blk, 0, stream>>>(ga, cH);
    }
    { float* tmp = af_r; af_r = afo_r; afo_r = tmp; }
    { float* tmp = af_g; af_g = afo_g; afo_g = tmp; }
  }

  // final iter: [Sa | Self] = relu(af @ [na | self])  (N=600)
  {
    GArgs6 ga{{
      gplain(af_r, cat2_h[0], cat2_l[0], RaU1_r, 600, Mres, cH, 320, 1),
      gplain(af_g, cat2_h[1], cat2_l[1], RaU1_g, 600, Mrg,  cH, 320, 1),
      zero, zero, zero, zero,
    }};
    gemm32<<<dim3(10, MT, 2), blk, 0, stream>>>(ga, 600);
  }
  kernels2_k<<<dim3(Mres + Mrg), dim3(320), 0, stream>>>(
      RaU1_r, Sb_r, res_ag, res_bg, res_nnb, res_mask, kern_r,
      RaU1_g, Sb_g, rg_ag, rg_bg, rg_nnb, rg_mask, kern_g);

  // U / V = kern @ W_att_h
  {
    GArgs6 ga{{
      gplain(kern_r, attT_h, attT_l, U, cH, Mres, cH, 320, 0),
      gplain(kern_g, attT_h, attT_l, V, cH, Mrg,  cH, 320, 0),
      zero, zero, zero, zero,
    }};
    gemm32<<<dim3(5, MT, 2), blk, 0, stream>>>(ga, cH);
  }
  att_ctx_h_k<<<dim3(cB * (cNR / AIT)), dim3(256), 0, stream>>>(
      U, V, W_att_s, kern_g, kern_r, qm, h760);

  score_mfma_k<<<dim3(13, cP / 64), blk, 0, stream>>>(
      h760, connect, core, sc0T_h, sc0T_l, W_score, out);
}